// Round 1
// baseline (646.880 us; speedup 1.0000x reference)
//
#include <hip/hip_runtime.h>

// LatentSensorMoE: fused bf16-MFMA expert MLPs + fp32 VALU gate path.
// B=32768, EIN=128, E=8, experts 128->512->256->128->1 (LN+SiLU per hidden),
// gate: 64->128(LN,SiLU)->128(LN,SiLU); enc 128->64(SiLU)->16; gating 144->128(LN,SiLU)->64(SiLU)->8->softmax.
// Outputs (fp32, concat): mixed[B] | z[B,16] | logits[B,8] | gates[B,8]

typedef __attribute__((ext_vector_type(8))) short bf16x8;   // 8 bf16 = 4 VGPR (guide-verified MFMA frag type)
typedef __attribute__((ext_vector_type(4))) short bf16x4;
typedef __attribute__((ext_vector_type(4))) float f32x4;

#define DEV static __device__ __forceinline__

DEV float b2f(unsigned short u){ union { unsigned int i; float f; } x; x.i = ((unsigned int)u) << 16; return x.f; }
DEV unsigned short f2b(float f){
  union { float f; unsigned int i; } x; x.f = f;
  return (unsigned short)((x.i + 0x7fffu + ((x.i >> 16) & 1u)) >> 16);  // RNE
}
DEV float silu_f(float v){ return v / (1.0f + __expf(-v)); }

// ---------------- pack kernels: fp32 -> bf16 MFMA fragment layouts ----------------
// A-frag (16x16x32): lane l holds A[m=l&15][k=(l>>4)*8+j], j=0..7  -> 16B/lane contiguous
// B-frag:            lane l holds B[k=(l>>4)*8+j][n=l&15]
// Stage s output is written to LDS in permuted k' order; W(s+1) k-dim is pre-permuted to match:
//  pi1: col c=(w*128+nt*16+c0) -> k' = w*128 + c0*8 + nt   (nt<8)
//  pi2: col c=(w*64 +nt*16+c0) -> k' = w*64  + c0*4 + nt   (nt<4)
//  pi3: col c=(w*32 +nt*16+c0) -> k' = w*32  + c0*2 + nt   (nt<2)

__global__ __launch_bounds__(256) void pack_x_kernel(const float* __restrict__ X, unsigned short* __restrict__ Xp){
  int t = blockIdx.x * 256 + threadIdx.x;          // [0, 2048*4*64)
  int l = t & 63, kb = (t >> 6) & 3, mtg = t >> 8; // mtg: 16-row tile id [0,2048)
  int row = mtg * 16 + (l & 15);
  int k0  = kb * 32 + (l >> 4) * 8;
  const float* src = X + (size_t)row * 128 + k0;
  bf16x8 o;
  #pragma unroll
  for (int j = 0; j < 8; j++) o[j] = (short)f2b(src[j]);
  *(bf16x8*)(Xp + (size_t)t * 8) = o;
}

__global__ __launch_bounds__(256) void pack_w1_kernel(const float* __restrict__ W, unsigned short* __restrict__ P){
  int t = blockIdx.x * 256 + threadIdx.x;          // [0, 65536)
  int l = t & 63, kb = (t >> 6) & 3, ntg = (t >> 8) & 31, e = t >> 13;
  int q = l >> 4, c0 = l & 15, n = ntg * 16 + c0;
  bf16x8 o;
  #pragma unroll
  for (int j = 0; j < 8; j++){ int k = kb*32 + q*8 + j; o[j] = (short)f2b(W[((size_t)e*128 + k)*512 + n]); }
  *(bf16x8*)(P + (size_t)t * 8) = o;
}

__global__ __launch_bounds__(256) void pack_w2_kernel(const float* __restrict__ W, unsigned short* __restrict__ P){
  int t = blockIdx.x * 256 + threadIdx.x;          // [0, 131072)
  int l = t & 63, kb = (t >> 6) & 15, ntg = (t >> 10) & 15, e = t >> 14;
  int q = l >> 4, c0 = l & 15, n = ntg * 16 + c0;
  bf16x8 o;
  #pragma unroll
  for (int j = 0; j < 8; j++){
    int kp = kb*32 + q*8 + j;                                        // k' in pi1 space
    int c = (kp >> 7) * 128 + (kp & 7) * 16 + ((kp >> 3) & 15);      // pi1^-1
    o[j] = (short)f2b(W[((size_t)e*512 + c)*256 + n]);
  }
  *(bf16x8*)(P + (size_t)t * 8) = o;
}

__global__ __launch_bounds__(256) void pack_w3_kernel(const float* __restrict__ W, unsigned short* __restrict__ P){
  int t = blockIdx.x * 256 + threadIdx.x;          // [0, 32768)
  int l = t & 63, kb = (t >> 6) & 7, ntg = (t >> 9) & 7, e = t >> 12;
  int q = l >> 4, c0 = l & 15, n = ntg * 16 + c0;
  bf16x8 o;
  #pragma unroll
  for (int j = 0; j < 8; j++){
    int kp = kb*32 + q*8 + j;                                        // k' in pi2 space
    int c = (kp >> 6) * 64 + (kp & 3) * 16 + ((kp >> 2) & 15);       // pi2^-1
    o[j] = (short)f2b(W[((size_t)e*256 + c)*128 + n]);
  }
  *(bf16x8*)(P + (size_t)t * 8) = o;
}

__global__ __launch_bounds__(256) void pack_w4_kernel(const float* __restrict__ W, float* __restrict__ P){
  int t = blockIdx.x * 256 + threadIdx.x;          // [0, 1024)
  if (t >= 1024) return;
  int e = t >> 7, kp = t & 127;
  int c = (kp >> 5) * 32 + (kp & 1) * 16 + ((kp >> 1) & 15);         // pi3^-1
  P[t] = W[e * 128 + c];
}

// ---------------- fused expert kernel: 32 rows x 1 expert per workgroup ----------------
// grid (1024, 8), 256 threads (4 waves). Waves split the N dim of each layer.
// LDS: h1[32][520] h2[32][264] h3[32][136] bf16 (+8 pad -> 2-way bank aliasing, free) ~60KB -> 2 wg/CU.
#define MFMA_BF16 __builtin_amdgcn_mfma_f32_16x16x32_bf16

__global__ __launch_bounds__(256, 2)
void expert_kernel(const unsigned short* __restrict__ Xp,
                   const unsigned short* __restrict__ W1p,
                   const unsigned short* __restrict__ W2p,
                   const unsigned short* __restrict__ W3p,
                   const float* __restrict__ w4p,
                   const float* __restrict__ eb1, const float* __restrict__ eg1, const float* __restrict__ ebt1,
                   const float* __restrict__ eb2, const float* __restrict__ eg2, const float* __restrict__ ebt2,
                   const float* __restrict__ eb3, const float* __restrict__ eg3, const float* __restrict__ ebt3,
                   const float* __restrict__ eb4, float* __restrict__ eo)
{
  const int e = blockIdx.y, bt = blockIdx.x;
  const int tid = threadIdx.x;
  const int w = tid >> 6, l = tid & 63;
  const int q = l >> 4, c0 = l & 15;

  __shared__ unsigned short h1[32 * 520];
  __shared__ unsigned short h2[32 * 264];
  __shared__ unsigned short h3[32 * 136];
  __shared__ float redS[32 * 4];
  __shared__ float redQ[32 * 4];
  __shared__ float muS[32];
  __shared__ float rsS[32];

  // ===== stage 1: X[32,128] @ W1[128,512], +b, LN, SiLU -> h1 (k' = pi1) =====
  {
    f32x4 acc[2][8];
    #pragma unroll
    for (int m = 0; m < 2; m++)
      #pragma unroll
      for (int nt = 0; nt < 8; nt++) acc[m][nt] = (f32x4){0.f,0.f,0.f,0.f};
    #pragma unroll
    for (int kb = 0; kb < 4; kb++){
      bf16x8 a0 = *(const bf16x8*)(Xp + ((size_t)((bt*2 + 0)*4 + kb)*64 + l)*8);
      bf16x8 a1 = *(const bf16x8*)(Xp + ((size_t)((bt*2 + 1)*4 + kb)*64 + l)*8);
      #pragma unroll
      for (int nt = 0; nt < 8; nt++){
        int ntg = w*8 + nt;
        bf16x8 b = *(const bf16x8*)(W1p + ((size_t)((e*32 + ntg)*4 + kb)*64 + l)*8);
        acc[0][nt] = MFMA_BF16(a0, b, acc[0][nt], 0, 0, 0);
        acc[1][nt] = MFMA_BF16(a1, b, acc[1][nt], 0, 0, 0);
      }
    }
    float bv[8], gv[8], tv[8];
    #pragma unroll
    for (int nt = 0; nt < 8; nt++){
      int col = w*128 + nt*16 + c0;
      bv[nt] = eb1[e*512 + col]; gv[nt] = eg1[e*512 + col]; tv[nt] = ebt1[e*512 + col];
    }
    float s[2][4] = {}, sq[2][4] = {};
    #pragma unroll
    for (int nt = 0; nt < 8; nt++)
      #pragma unroll
      for (int m = 0; m < 2; m++)
        #pragma unroll
        for (int r = 0; r < 4; r++){
          float v = acc[m][nt][r] + bv[nt];
          acc[m][nt][r] = v; s[m][r] += v; sq[m][r] += v*v;
        }
    #pragma unroll
    for (int m = 0; m < 2; m++)
      #pragma unroll
      for (int r = 0; r < 4; r++){
        float a = s[m][r], b = sq[m][r];
        #pragma unroll
        for (int off = 1; off < 16; off <<= 1){ a += __shfl_xor(a, off, 64); b += __shfl_xor(b, off, 64); }
        if (c0 == 0){ int row = m*16 + q*4 + r; redS[row*4 + w] = a; redQ[row*4 + w] = b; }
      }
    __syncthreads();
    if (tid < 32){
      float S = 0.f, Q = 0.f;
      #pragma unroll
      for (int i = 0; i < 4; i++){ S += redS[tid*4 + i]; Q += redQ[tid*4 + i]; }
      float mu = S * (1.0f/512.0f);
      float var = Q * (1.0f/512.0f) - mu*mu;
      muS[tid] = mu; rsS[tid] = rsqrtf(var + 1e-5f);
    }
    __syncthreads();
    #pragma unroll
    for (int m = 0; m < 2; m++)
      #pragma unroll
      for (int r = 0; r < 4; r++){
        int row = m*16 + q*4 + r;
        float mu = muS[row], rs = rsS[row];
        bf16x8 pk;
        #pragma unroll
        for (int nt = 0; nt < 8; nt++){
          float v = (acc[m][nt][r] - mu) * rs * gv[nt] + tv[nt];
          pk[nt] = (short)f2b(silu_f(v));
        }
        *(bf16x8*)(h1 + row*520 + w*128 + c0*8) = pk;   // ds_write_b128, k' = w*128+c0*8+nt
      }
  }
  __syncthreads();

  // ===== stage 2: h1[32,512(pi1)] @ W2p, +b, LN, SiLU -> h2 (k' = pi2) =====
  {
    f32x4 acc[2][4];
    #pragma unroll
    for (int m = 0; m < 2; m++)
      #pragma unroll
      for (int nt = 0; nt < 4; nt++) acc[m][nt] = (f32x4){0.f,0.f,0.f,0.f};
    #pragma unroll 2
    for (int kb = 0; kb < 16; kb++){
      bf16x8 a0 = *(const bf16x8*)(h1 + (0  + c0)*520 + kb*32 + q*8);
      bf16x8 a1 = *(const bf16x8*)(h1 + (16 + c0)*520 + kb*32 + q*8);
      #pragma unroll
      for (int nt = 0; nt < 4; nt++){
        int ntg = w*4 + nt;
        bf16x8 b = *(const bf16x8*)(W2p + ((size_t)((e*16 + ntg)*16 + kb)*64 + l)*8);
        acc[0][nt] = MFMA_BF16(a0, b, acc[0][nt], 0, 0, 0);
        acc[1][nt] = MFMA_BF16(a1, b, acc[1][nt], 0, 0, 0);
      }
    }
    float bv[4], gv[4], tv[4];
    #pragma unroll
    for (int nt = 0; nt < 4; nt++){
      int col = w*64 + nt*16 + c0;
      bv[nt] = eb2[e*256 + col]; gv[nt] = eg2[e*256 + col]; tv[nt] = ebt2[e*256 + col];
    }
    float s[2][4] = {}, sq[2][4] = {};
    #pragma unroll
    for (int nt = 0; nt < 4; nt++)
      #pragma unroll
      for (int m = 0; m < 2; m++)
        #pragma unroll
        for (int r = 0; r < 4; r++){
          float v = acc[m][nt][r] + bv[nt];
          acc[m][nt][r] = v; s[m][r] += v; sq[m][r] += v*v;
        }
    #pragma unroll
    for (int m = 0; m < 2; m++)
      #pragma unroll
      for (int r = 0; r < 4; r++){
        float a = s[m][r], b = sq[m][r];
        #pragma unroll
        for (int off = 1; off < 16; off <<= 1){ a += __shfl_xor(a, off, 64); b += __shfl_xor(b, off, 64); }
        if (c0 == 0){ int row = m*16 + q*4 + r; redS[row*4 + w] = a; redQ[row*4 + w] = b; }
      }
    __syncthreads();
    if (tid < 32){
      float S = 0.f, Q = 0.f;
      #pragma unroll
      for (int i = 0; i < 4; i++){ S += redS[tid*4 + i]; Q += redQ[tid*4 + i]; }
      float mu = S * (1.0f/256.0f);
      float var = Q * (1.0f/256.0f) - mu*mu;
      muS[tid] = mu; rsS[tid] = rsqrtf(var + 1e-5f);
    }
    __syncthreads();
    #pragma unroll
    for (int m = 0; m < 2; m++)
      #pragma unroll
      for (int r = 0; r < 4; r++){
        int row = m*16 + q*4 + r;
        float mu = muS[row], rs = rsS[row];
        bf16x4 pk;
        #pragma unroll
        for (int nt = 0; nt < 4; nt++){
          float v = (acc[m][nt][r] - mu) * rs * gv[nt] + tv[nt];
          pk[nt] = (short)f2b(silu_f(v));
        }
        *(bf16x4*)(h2 + row*264 + w*64 + c0*4) = pk;    // ds_write_b64, k' = w*64+c0*4+nt
      }
  }
  __syncthreads();

  // ===== stage 3: h2[32,256(pi2)] @ W3p, +b, LN, SiLU -> h3 (k' = pi3) =====
  {
    f32x4 acc[2][2];
    #pragma unroll
    for (int m = 0; m < 2; m++)
      #pragma unroll
      for (int nt = 0; nt < 2; nt++) acc[m][nt] = (f32x4){0.f,0.f,0.f,0.f};
    #pragma unroll 2
    for (int kb = 0; kb < 8; kb++){
      bf16x8 a0 = *(const bf16x8*)(h2 + (0  + c0)*264 + kb*32 + q*8);
      bf16x8 a1 = *(const bf16x8*)(h2 + (16 + c0)*264 + kb*32 + q*8);
      #pragma unroll
      for (int nt = 0; nt < 2; nt++){
        int ntg = w*2 + nt;
        bf16x8 b = *(const bf16x8*)(W3p + ((size_t)((e*8 + ntg)*8 + kb)*64 + l)*8);
        acc[0][nt] = MFMA_BF16(a0, b, acc[0][nt], 0, 0, 0);
        acc[1][nt] = MFMA_BF16(a1, b, acc[1][nt], 0, 0, 0);
      }
    }
    float bv[2], gv[2], tv[2];
    #pragma unroll
    for (int nt = 0; nt < 2; nt++){
      int col = w*32 + nt*16 + c0;
      bv[nt] = eb3[e*128 + col]; gv[nt] = eg3[e*128 + col]; tv[nt] = ebt3[e*128 + col];
    }
    float s[2][4] = {}, sq[2][4] = {};
    #pragma unroll
    for (int nt = 0; nt < 2; nt++)
      #pragma unroll
      for (int m = 0; m < 2; m++)
        #pragma unroll
        for (int r = 0; r < 4; r++){
          float v = acc[m][nt][r] + bv[nt];
          acc[m][nt][r] = v; s[m][r] += v; sq[m][r] += v*v;
        }
    #pragma unroll
    for (int m = 0; m < 2; m++)
      #pragma unroll
      for (int r = 0; r < 4; r++){
        float a = s[m][r], b = sq[m][r];
        #pragma unroll
        for (int off = 1; off < 16; off <<= 1){ a += __shfl_xor(a, off, 64); b += __shfl_xor(b, off, 64); }
        if (c0 == 0){ int row = m*16 + q*4 + r; redS[row*4 + w] = a; redQ[row*4 + w] = b; }
      }
    __syncthreads();
    if (tid < 32){
      float S = 0.f, Q = 0.f;
      #pragma unroll
      for (int i = 0; i < 4; i++){ S += redS[tid*4 + i]; Q += redQ[tid*4 + i]; }
      float mu = S * (1.0f/128.0f);
      float var = Q * (1.0f/128.0f) - mu*mu;
      muS[tid] = mu; rsS[tid] = rsqrtf(var + 1e-5f);
    }
    __syncthreads();
    #pragma unroll
    for (int m = 0; m < 2; m++)
      #pragma unroll
      for (int r = 0; r < 4; r++){
        int row = m*16 + q*4 + r;
        float mu = muS[row], rs = rsS[row];
        float v0 = silu_f((acc[m][0][r] - mu) * rs * gv[0] + tv[0]);
        float v1 = silu_f((acc[m][1][r] - mu) * rs * gv[1] + tv[1]);
        unsigned int pr = ((unsigned int)f2b(v1) << 16) | (unsigned int)f2b(v0);
        *(unsigned int*)(h3 + row*136 + w*32 + c0*2) = pr;  // ds_write_b32, k' = w*32+c0*2+nt
      }
  }
  __syncthreads();

  // ===== stage 4: h3[32,128(pi3)] . w4p[e] + eb4 -> eo[b, e] =====
  {
    int row = tid >> 3, sub = tid & 7;
    bf16x8 v0 = *(const bf16x8*)(h3 + row*136 + sub*16);
    bf16x8 v1 = *(const bf16x8*)(h3 + row*136 + sub*16 + 8);
    float a = 0.f;
    #pragma unroll
    for (int j = 0; j < 8; j++) a += b2f((unsigned short)v0[j]) * w4p[e*128 + sub*16 + j];
    #pragma unroll
    for (int j = 0; j < 8; j++) a += b2f((unsigned short)v1[j]) * w4p[e*128 + sub*16 + 8 + j];
    a += __shfl_xor(a, 1, 64); a += __shfl_xor(a, 2, 64); a += __shfl_xor(a, 4, 64);
    if (sub == 0) eo[(size_t)(bt*32 + row)*8 + e] = a + eb4[e];
  }
}

// ---------------- gate path: generic fp32 layer kernel, 16 rows/block ----------------
// FIN=1: fused second GEMM (N->N2) no act (encoder z). FIN=2: second GEMM -> logits + softmax -> gates.
template<int K1, int K2, int N, int LN, int ACT, int IN1F32, int OUTBF16, int FIN, int N2>
__global__ __launch_bounds__(256)
void gate_kernel(const void* __restrict__ X1v, const float* __restrict__ X2,
                 const float* __restrict__ W, const float* __restrict__ bias,
                 const float* __restrict__ g, const float* __restrict__ bt,
                 void* __restrict__ outv,
                 const float* __restrict__ W2, const float* __restrict__ b2,
                 float* __restrict__ out2a, float* __restrict__ out2b)
{
  constexpr int K = K1 + K2;
  constexpr int LGN = __builtin_ctz(N);
  constexpr int NOUT = (16 * N) / 256;   // outputs per thread (N=128 -> 8, N=64 -> 4)
  constexpr int RS = 256 >> LGN;

  __shared__ float xs[16][K + 1];
  __shared__ float ys[16][N];
  __shared__ float mu_s[16], rs_s[16];
  __shared__ float ps[16][4], pq[16][4];

  const int tid = threadIdx.x;
  const int row0 = blockIdx.x * 16;

  if constexpr (IN1F32){
    const float* X1 = (const float*)X1v;
    for (int idx = tid; idx < 16*K1; idx += 256){ int r = idx / K1, k = idx - r*K1; xs[r][k] = X1[(size_t)(row0+r)*K1 + k]; }
  } else {
    const unsigned short* X1 = (const unsigned short*)X1v;
    for (int idx = tid; idx < 16*K1; idx += 256){ int r = idx / K1, k = idx - r*K1; xs[r][k] = b2f(X1[(size_t)(row0+r)*K1 + k]); }
  }
  if constexpr (K2 > 0){
    for (int idx = tid; idx < 16*K2; idx += 256){ int r = idx / K2, k = idx - r*K2; xs[r][K1+k] = X2[(size_t)(row0+r)*K2 + k]; }
  }
  __syncthreads();

  const int j = tid & (N - 1);
  const int rbase = tid >> LGN;

  float acc[NOUT];
  #pragma unroll
  for (int i = 0; i < NOUT; i++) acc[i] = bias[j];
  for (int k = 0; k < K; k++){
    float wv = W[(size_t)k * N + j];
    #pragma unroll
    for (int i = 0; i < NOUT; i++) acc[i] += xs[rbase + i*RS][k] * wv;
  }

  if constexpr (LN){
    #pragma unroll
    for (int i = 0; i < NOUT; i++) ys[rbase + i*RS][j] = acc[i];
    __syncthreads();
    if (tid < 64){
      int r = tid >> 2, part = tid & 3;
      float S = 0.f, Q = 0.f;
      for (int k = part*(N/4); k < (part+1)*(N/4); k++){ float v = ys[r][k]; S += v; Q += v*v; }
      ps[r][part] = S; pq[r][part] = Q;
    }
    __syncthreads();
    if (tid < 16){
      float S = 0.f, Q = 0.f;
      #pragma unroll
      for (int i = 0; i < 4; i++){ S += ps[tid][i]; Q += pq[tid][i]; }
      float mu = S * (1.0f / N);
      float var = Q * (1.0f / N) - mu*mu;
      mu_s[tid] = mu; rs_s[tid] = rsqrtf(var + 1e-5f);
    }
    __syncthreads();
    #pragma unroll
    for (int i = 0; i < NOUT; i++){
      int r = rbase + i*RS;
      float v = (acc[i] - mu_s[r]) * rs_s[r] * g[j] + bt[j];
      if (ACT) v = silu_f(v);
      acc[i] = v;
    }
  } else {
    if constexpr (ACT){
      #pragma unroll
      for (int i = 0; i < NOUT; i++) acc[i] = silu_f(acc[i]);
    }
  }

  if constexpr (FIN == 0){
    if constexpr (OUTBF16){
      unsigned short* out = (unsigned short*)outv;
      #pragma unroll
      for (int i = 0; i < NOUT; i++){ int r = rbase + i*RS; out[(size_t)(row0 + r)*N + j] = f2b(acc[i]); }
    } else {
      float* out = (float*)outv;
      #pragma unroll
      for (int i = 0; i < NOUT; i++){ int r = rbase + i*RS; out[(size_t)(row0 + r)*N + j] = acc[i]; }
    }
  } else {
    #pragma unroll
    for (int i = 0; i < NOUT; i++) ys[rbase + i*RS][j] = acc[i];
    __syncthreads();
    if constexpr (FIN == 1){
      if (tid < 16*N2){
        int r = tid / N2, j2 = tid % N2;
        float a = b2[j2];
        for (int k = 0; k < N; k++) a += ys[r][k] * W2[k*N2 + j2];
        out2a[(size_t)(row0 + r)*N2 + j2] = a;
      }
    } else {
      __shared__ float ls[16][8];
      if (tid < 128){
        int r = tid >> 3, j2 = tid & 7;
        float a = b2[j2];
        for (int k = 0; k < N; k++) a += ys[r][k] * W2[k*8 + j2];
        ls[r][j2] = a;
        out2a[(size_t)(row0 + r)*8 + j2] = a;              // logits (raw)
      }
      __syncthreads();
      if (tid < 16){
        float m = -1e30f;
        #pragma unroll
        for (int i2 = 0; i2 < 8; i2++) m = fmaxf(m, ls[tid][i2]);
        float ex[8], ssum = 0.f;
        #pragma unroll
        for (int i2 = 0; i2 < 8; i2++){ ex[i2] = __expf(ls[tid][i2] - m); ssum += ex[i2]; }
        float inv = 1.0f / ssum;
        #pragma unroll
        for (int i2 = 0; i2 < 8; i2++) out2b[(size_t)(row0 + tid)*8 + i2] = ex[i2] * inv;  // gates
      }
    }
  }
}

// ---------------- final mix: mixed[b] = sum_e eo[b,e]*gates[b,e] ----------------
__global__ __launch_bounds__(256) void mix_kernel(const float* __restrict__ eo, const float* __restrict__ gates,
                                                  float* __restrict__ mixed){
  int t = blockIdx.x * 256 + threadIdx.x;
  if (t < 32768){
    const float4* a = (const float4*)(eo + (size_t)t*8);
    const float4* gg = (const float4*)(gates + (size_t)t*8);
    float4 a0 = a[0], a1 = a[1], g0 = gg[0], g1 = gg[1];
    mixed[t] = a0.x*g0.x + a0.y*g0.y + a0.z*g0.z + a0.w*g0.w
             + a1.x*g1.x + a1.y*g1.y + a1.z*g1.z + a1.w*g1.w;
  }
}

extern "C" void kernel_launch(void* const* d_in, const int* in_sizes, int n_in,
                              void* d_out, int out_size, void* d_ws, size_t ws_size,
                              hipStream_t stream)
{
  if (n_in < 36 || in_sizes[0] != 32768*128 || out_size < 1081344) return;

  const float* expert_features = (const float*)d_in[0];
  const float* gate_features   = (const float*)d_in[1];
  const float* eW1 = (const float*)d_in[2];
  const float* eb1 = (const float*)d_in[3];
  const float* eg1 = (const float*)d_in[4];
  const float* ebt1= (const float*)d_in[5];
  const float* eW2 = (const float*)d_in[6];
  const float* eb2 = (const float*)d_in[7];
  const float* eg2 = (const float*)d_in[8];
  const float* ebt2= (const float*)d_in[9];
  const float* eW3 = (const float*)d_in[10];
  const float* eb3 = (const float*)d_in[11];
  const float* eg3 = (const float*)d_in[12];
  const float* ebt3= (const float*)d_in[13];
  const float* eW4 = (const float*)d_in[14];
  const float* eb4 = (const float*)d_in[15];
  const float* bW1 = (const float*)d_in[16];
  const float* bb1 = (const float*)d_in[17];
  const float* bg1 = (const float*)d_in[18];
  const float* bbt1= (const float*)d_in[19];
  const float* bW2 = (const float*)d_in[20];
  const float* bb2 = (const float*)d_in[21];
  const float* bg2 = (const float*)d_in[22];
  const float* bbt2= (const float*)d_in[23];
  const float* encW1 = (const float*)d_in[24];
  const float* encb1 = (const float*)d_in[25];
  const float* encW2 = (const float*)d_in[26];
  const float* encb2 = (const float*)d_in[27];
  const float* gW1 = (const float*)d_in[28];
  const float* gb1 = (const float*)d_in[29];
  const float* gg1 = (const float*)d_in[30];
  const float* gbt1= (const float*)d_in[31];
  const float* gW2 = (const float*)d_in[32];
  const float* gb2 = (const float*)d_in[33];
  const float* gW3 = (const float*)d_in[34];
  const float* gb3 = (const float*)d_in[35];

  float* out        = (float*)d_out;
  float* out_mixed  = out;                 // [B]
  float* out_z      = out + 32768;         // [B,16]
  float* out_logits = out + 557056;        // [B,8]
  float* out_gates  = out + 819200;        // [B,8]

  char* ws = (char*)d_ws;
  size_t off = 0;
  auto walloc = [&](size_t bytes) -> char* { char* p = ws + off; off += (bytes + 255) & ~(size_t)255; return p; };
  unsigned short* Xp  = (unsigned short*)walloc((size_t)4194304 * 2);  // packed X, bf16
  unsigned short* W1p = (unsigned short*)walloc((size_t)524288  * 2);
  unsigned short* W2p = (unsigned short*)walloc((size_t)1048576 * 2);
  unsigned short* W3p = (unsigned short*)walloc((size_t)262144  * 2);
  float*          w4p = (float*)walloc((size_t)1024 * 4);
  unsigned short* wsA = (unsigned short*)walloc((size_t)4194304 * 2);  // gh1 / gg1 (aliased), bf16 [B,128]
  unsigned short* wsB = (unsigned short*)walloc((size_t)4194304 * 2);  // gh2, bf16 [B,128]
  float*          eo  = (float*)walloc((size_t)262144 * 4);            // expert outputs [B,8]
  if (off > ws_size) return;  // workspace too small -> clean failure signal

  // --- pack (weights small; rerun every call, ~5us) ---
  pack_x_kernel <<<2048, 256, 0, stream>>>(expert_features, Xp);
  pack_w1_kernel<<< 256, 256, 0, stream>>>(eW1, W1p);
  pack_w2_kernel<<< 512, 256, 0, stream>>>(eW2, W2p);
  pack_w3_kernel<<< 128, 256, 0, stream>>>(eW3, W3p);
  pack_w4_kernel<<<   4, 256, 0, stream>>>(eW4, w4p);

  // --- gate path (fp32 VALU) ---
  gate_kernel<64,0,128,1,1,1,1,0,1><<<2048, 256, 0, stream>>>(gate_features, nullptr, bW1, bb1, bg1, bbt1, wsA, nullptr, nullptr, nullptr, nullptr);
  gate_kernel<128,0,128,1,1,0,1,0,1><<<2048, 256, 0, stream>>>(wsA, nullptr, bW2, bb2, bg2, bbt2, wsB, nullptr, nullptr, nullptr, nullptr);
  gate_kernel<128,0,64,0,1,0,0,1,16><<<2048, 256, 0, stream>>>(wsB, nullptr, encW1, encb1, nullptr, nullptr, nullptr, encW2, encb2, out_z, nullptr);
  gate_kernel<128,16,128,1,1,0,1,0,1><<<2048, 256, 0, stream>>>(wsB, out_z, gW1, gb1, gg1, gbt1, wsA, nullptr, nullptr, nullptr, nullptr);
  gate_kernel<128,0,64,0,1,0,0,2,8><<<2048, 256, 0, stream>>>(wsA, nullptr, gW2, gb2, nullptr, nullptr, nullptr, gW3, gb3, out_logits, out_gates);

  // --- fused experts (bf16 MFMA) ---
  expert_kernel<<<dim3(1024, 8), 256, 0, stream>>>(Xp, W1p, W2p, W3p, w4p,
                                                   eb1, eg1, ebt1, eb2, eg2, ebt2, eb3, eg3, ebt3,
                                                   eb4, eo);

  // --- mix ---
  mix_kernel<<<128, 256, 0, stream>>>(eo, out_gates, out_mixed);
}

// Round 2
// 500.587 us; speedup vs baseline: 1.2922x; 1.2922x over previous
//
#include <hip/hip_runtime.h>
#include <hip/hip_bf16.h>

// LatentSensorMoE: fused bf16-MFMA expert MLPs + fused fp32 gate path.
// B=32768, EIN=128, E=8, experts 128->512->256->128->1 (LN+SiLU per hidden),
// gate: 64->128(LN,SiLU)->128(LN,SiLU); enc 128->64(SiLU)->16; gating 144->128(LN,SiLU)->64(SiLU)->8->softmax.
// Outputs (fp32, concat): mixed[B] | z[B,16] | logits[B,8] | gates[B,8]

typedef __attribute__((ext_vector_type(8))) short bf16x8;   // 8 bf16 = 4 VGPR (MFMA frag)
typedef __attribute__((ext_vector_type(4))) float f32x4;

#define DEV static __device__ __forceinline__

DEV float b2f(unsigned short u){ union { unsigned int i; float f; } x; x.i = ((unsigned int)u) << 16; return x.f; }
DEV unsigned short f2b(float f){
  union { float f; unsigned int i; } x; x.f = f;
  return (unsigned short)((x.i + 0x7fffu + ((x.i >> 16) & 1u)) >> 16);  // RNE
}
DEV unsigned int pk2(float a, float b){
  __hip_bfloat162 h = __float22bfloat162_rn(make_float2(a, b));        // v_cvt_pk_bf16_f32
  union { __hip_bfloat162 h; unsigned int u; } u; u.h = h; return u.u;
}
DEV float silu_f(float v){ return v / (1.0f + __expf(-v)); }

// ---------------- pack kernels: fp32 -> bf16 MFMA fragment layouts ----------------
// A-frag (16x16x32): lane l holds A[m=l&15][k=(l>>4)*8+j], j=0..7  -> 16B/lane contiguous
// B-frag:            lane l holds B[k=(l>>4)*8+j][n=l&15]
// Stage s output is written to LDS in permuted k' order; W(s+1) k-dim pre-permuted to match:
//  pi1: col c=(w*128+nt*16+c0) -> k' = w*128 + c0*8 + nt   (nt<8)
//  pi2: col c=(w*64 +nt*16+c0) -> k' = w*64  + c0*4 + nt   (nt<4)
//  pi3: col c=(w*32 +nt*16+c0) -> k' = w*32  + c0*2 + nt   (nt<2)

__global__ __launch_bounds__(256) void pack_x_kernel(const float* __restrict__ X, unsigned short* __restrict__ Xp){
  int t = blockIdx.x * 256 + threadIdx.x;          // [0, 2048*4*64)
  int l = t & 63, kb = (t >> 6) & 3, mtg = t >> 8; // mtg: 16-row tile id [0,2048)
  int row = mtg * 16 + (l & 15);
  int k0  = kb * 32 + (l >> 4) * 8;
  const float* src = X + (size_t)row * 128 + k0;
  bf16x8 o;
  #pragma unroll
  for (int j = 0; j < 8; j++) o[j] = (short)f2b(src[j]);
  *(bf16x8*)(Xp + (size_t)t * 8) = o;
}

// combined weight pack: blocks [0,256)=W1, [256,768)=W2, [768,896)=W3, [896,900)=w4
__global__ __launch_bounds__(256) void pack_w_kernel(const float* __restrict__ eW1, const float* __restrict__ eW2,
                                                     const float* __restrict__ eW3, const float* __restrict__ eW4,
                                                     unsigned short* __restrict__ W1p, unsigned short* __restrict__ W2p,
                                                     unsigned short* __restrict__ W3p, float* __restrict__ w4p){
  int b = blockIdx.x;
  if (b < 256){
    int t = b * 256 + threadIdx.x;                 // [0, 65536)
    int l = t & 63, kb = (t >> 6) & 3, ntg = (t >> 8) & 31, e = t >> 13;
    int q = l >> 4, c0 = l & 15, n = ntg * 16 + c0;
    bf16x8 o;
    #pragma unroll
    for (int j = 0; j < 8; j++){ int k = kb*32 + q*8 + j; o[j] = (short)f2b(eW1[((size_t)e*128 + k)*512 + n]); }
    *(bf16x8*)(W1p + (size_t)t * 8) = o;
  } else if (b < 768){
    int t = (b - 256) * 256 + threadIdx.x;         // [0, 131072)
    int l = t & 63, kb = (t >> 6) & 15, ntg = (t >> 10) & 15, e = t >> 14;
    int q = l >> 4, c0 = l & 15, n = ntg * 16 + c0;
    bf16x8 o;
    #pragma unroll
    for (int j = 0; j < 8; j++){
      int kp = kb*32 + q*8 + j;                                        // k' in pi1 space
      int c = (kp >> 7) * 128 + (kp & 7) * 16 + ((kp >> 3) & 15);      // pi1^-1
      o[j] = (short)f2b(eW2[((size_t)e*512 + c)*256 + n]);
    }
    *(bf16x8*)(W2p + (size_t)t * 8) = o;
  } else if (b < 896){
    int t = (b - 768) * 256 + threadIdx.x;         // [0, 32768)
    int l = t & 63, kb = (t >> 6) & 7, ntg = (t >> 9) & 7, e = t >> 12;
    int q = l >> 4, c0 = l & 15, n = ntg * 16 + c0;
    bf16x8 o;
    #pragma unroll
    for (int j = 0; j < 8; j++){
      int kp = kb*32 + q*8 + j;                                        // k' in pi2 space
      int c = (kp >> 6) * 64 + (kp & 3) * 16 + ((kp >> 2) & 15);       // pi2^-1
      o[j] = (short)f2b(eW3[((size_t)e*256 + c)*128 + n]);
    }
    *(bf16x8*)(W3p + (size_t)t * 8) = o;
  } else {
    int t = (b - 896) * 256 + threadIdx.x;
    if (t < 1024){
      int e = t >> 7, kp = t & 127;
      int c = (kp >> 5) * 32 + (kp & 1) * 16 + ((kp >> 1) & 15);       // pi3^-1
      w4p[t] = eW4[e * 128 + c];
    }
  }
}

// ---------------- fused expert kernel: 32 rows x 1 expert per workgroup ----------------
// grid (1024, 8), 256 threads (4 waves). Waves split the N dim of each layer.
// LDS: h1[32][520] bf16 (33.3KB, h3 aliases it), h2[32][264] (16.9KB), +1.3KB scratch
//  => 51.5KB -> 3 wg/CU (was 60.4KB -> 2 wg/CU; occupancy was the round-1 limiter).
#define MFMA_BF16 __builtin_amdgcn_mfma_f32_16x16x32_bf16

__global__ __launch_bounds__(256, 3)
void expert_kernel(const unsigned short* __restrict__ Xp,
                   const unsigned short* __restrict__ W1p,
                   const unsigned short* __restrict__ W2p,
                   const unsigned short* __restrict__ W3p,
                   const float* __restrict__ w4p,
                   const float* __restrict__ eb1, const float* __restrict__ eg1, const float* __restrict__ ebt1,
                   const float* __restrict__ eb2, const float* __restrict__ eg2, const float* __restrict__ ebt2,
                   const float* __restrict__ eb3, const float* __restrict__ eg3, const float* __restrict__ ebt3,
                   const float* __restrict__ eb4, float* __restrict__ eo)
{
  const int e = blockIdx.y, bt = blockIdx.x;
  const int tid = threadIdx.x;
  const int w = tid >> 6, l = tid & 63;
  const int q = l >> 4, c0 = l & 15;

  __shared__ __align__(16) unsigned short h1[32 * 520];  // h3 aliases h1 (h1 dead after stage-2 k-loop)
  __shared__ __align__(16) unsigned short h2[32 * 264];
  __shared__ float redS[32 * 4];
  __shared__ float redQ[32 * 4];
  __shared__ float muS[32];
  __shared__ float rsS[32];
  unsigned short* h3 = h1;

  // ===== stage 1: X[32,128] @ W1[128,512], +b (as C-init), LN, SiLU -> h1 (k' = pi1) =====
  {
    float bv[8], gv[8], tv[8];
    #pragma unroll
    for (int nt = 0; nt < 8; nt++){
      int col = w*128 + nt*16 + c0;
      bv[nt] = eb1[e*512 + col]; gv[nt] = eg1[e*512 + col]; tv[nt] = ebt1[e*512 + col];
    }
    f32x4 acc[2][8];
    #pragma unroll
    for (int m = 0; m < 2; m++)
      #pragma unroll
      for (int nt = 0; nt < 8; nt++) acc[m][nt] = (f32x4){bv[nt],bv[nt],bv[nt],bv[nt]};
    #pragma unroll
    for (int kb = 0; kb < 4; kb++){
      bf16x8 a0 = *(const bf16x8*)(Xp + ((size_t)((bt*2 + 0)*4 + kb)*64 + l)*8);
      bf16x8 a1 = *(const bf16x8*)(Xp + ((size_t)((bt*2 + 1)*4 + kb)*64 + l)*8);
      #pragma unroll
      for (int nt = 0; nt < 8; nt++){
        int ntg = w*8 + nt;
        bf16x8 b = *(const bf16x8*)(W1p + ((size_t)((e*32 + ntg)*4 + kb)*64 + l)*8);
        acc[0][nt] = MFMA_BF16(a0, b, acc[0][nt], 0, 0, 0);
        acc[1][nt] = MFMA_BF16(a1, b, acc[1][nt], 0, 0, 0);
      }
    }
    float s[2][4] = {}, sq[2][4] = {};
    #pragma unroll
    for (int nt = 0; nt < 8; nt++)
      #pragma unroll
      for (int m = 0; m < 2; m++)
        #pragma unroll
        for (int r = 0; r < 4; r++){
          float v = acc[m][nt][r];
          s[m][r] += v; sq[m][r] += v*v;
        }
    #pragma unroll
    for (int m = 0; m < 2; m++)
      #pragma unroll
      for (int r = 0; r < 4; r++){
        float a = s[m][r], b = sq[m][r];
        #pragma unroll
        for (int off = 1; off < 16; off <<= 1){ a += __shfl_xor(a, off, 64); b += __shfl_xor(b, off, 64); }
        if (c0 == 0){ int row = m*16 + q*4 + r; redS[row*4 + w] = a; redQ[row*4 + w] = b; }
      }
    __syncthreads();
    if (tid < 32){
      float S = 0.f, Q = 0.f;
      #pragma unroll
      for (int i = 0; i < 4; i++){ S += redS[tid*4 + i]; Q += redQ[tid*4 + i]; }
      float mu = S * (1.0f/512.0f);
      float var = Q * (1.0f/512.0f) - mu*mu;
      muS[tid] = mu; rsS[tid] = rsqrtf(var + 1e-5f);
    }
    __syncthreads();
    #pragma unroll
    for (int m = 0; m < 2; m++)
      #pragma unroll
      for (int r = 0; r < 4; r++){
        int row = m*16 + q*4 + r;
        float mu = muS[row], rs = rsS[row];
        float v[8];
        #pragma unroll
        for (int nt = 0; nt < 8; nt++) v[nt] = silu_f((acc[m][nt][r] - mu) * rs * gv[nt] + tv[nt]);
        uint4 pk;
        pk.x = pk2(v[0], v[1]); pk.y = pk2(v[2], v[3]); pk.z = pk2(v[4], v[5]); pk.w = pk2(v[6], v[7]);
        *(uint4*)(h1 + row*520 + w*128 + c0*8) = pk;   // ds_write_b128, k' = w*128+c0*8+nt
      }
  }
  __syncthreads();

  // ===== stage 2: h1[32,512(pi1)] @ W2p, +b, LN, SiLU -> h2 (k' = pi2) =====
  {
    float bv[4], gv[4], tv[4];
    #pragma unroll
    for (int nt = 0; nt < 4; nt++){
      int col = w*64 + nt*16 + c0;
      bv[nt] = eb2[e*256 + col]; gv[nt] = eg2[e*256 + col]; tv[nt] = ebt2[e*256 + col];
    }
    f32x4 acc[2][4];
    #pragma unroll
    for (int m = 0; m < 2; m++)
      #pragma unroll
      for (int nt = 0; nt < 4; nt++) acc[m][nt] = (f32x4){bv[nt],bv[nt],bv[nt],bv[nt]};
    #pragma unroll 2
    for (int kb = 0; kb < 16; kb++){
      bf16x8 a0 = *(const bf16x8*)(h1 + (0  + c0)*520 + kb*32 + q*8);
      bf16x8 a1 = *(const bf16x8*)(h1 + (16 + c0)*520 + kb*32 + q*8);
      #pragma unroll
      for (int nt = 0; nt < 4; nt++){
        int ntg = w*4 + nt;
        bf16x8 b = *(const bf16x8*)(W2p + ((size_t)((e*16 + ntg)*16 + kb)*64 + l)*8);
        acc[0][nt] = MFMA_BF16(a0, b, acc[0][nt], 0, 0, 0);
        acc[1][nt] = MFMA_BF16(a1, b, acc[1][nt], 0, 0, 0);
      }
    }
    float s[2][4] = {}, sq[2][4] = {};
    #pragma unroll
    for (int nt = 0; nt < 4; nt++)
      #pragma unroll
      for (int m = 0; m < 2; m++)
        #pragma unroll
        for (int r = 0; r < 4; r++){
          float v = acc[m][nt][r];
          s[m][r] += v; sq[m][r] += v*v;
        }
    #pragma unroll
    for (int m = 0; m < 2; m++)
      #pragma unroll
      for (int r = 0; r < 4; r++){
        float a = s[m][r], b = sq[m][r];
        #pragma unroll
        for (int off = 1; off < 16; off <<= 1){ a += __shfl_xor(a, off, 64); b += __shfl_xor(b, off, 64); }
        if (c0 == 0){ int row = m*16 + q*4 + r; redS[row*4 + w] = a; redQ[row*4 + w] = b; }
      }
    __syncthreads();
    if (tid < 32){
      float S = 0.f, Q = 0.f;
      #pragma unroll
      for (int i = 0; i < 4; i++){ S += redS[tid*4 + i]; Q += redQ[tid*4 + i]; }
      float mu = S * (1.0f/256.0f);
      float var = Q * (1.0f/256.0f) - mu*mu;
      muS[tid] = mu; rsS[tid] = rsqrtf(var + 1e-5f);
    }
    __syncthreads();
    #pragma unroll
    for (int m = 0; m < 2; m++)
      #pragma unroll
      for (int r = 0; r < 4; r++){
        int row = m*16 + q*4 + r;
        float mu = muS[row], rs = rsS[row];
        float v[4];
        #pragma unroll
        for (int nt = 0; nt < 4; nt++) v[nt] = silu_f((acc[m][nt][r] - mu) * rs * gv[nt] + tv[nt]);
        uint2 pk; pk.x = pk2(v[0], v[1]); pk.y = pk2(v[2], v[3]);
        *(uint2*)(h2 + row*264 + w*64 + c0*4) = pk;    // ds_write_b64, k' = w*64+c0*4+nt
      }
  }
  __syncthreads();

  // ===== stage 3: h2[32,256(pi2)] @ W3p, +b, LN, SiLU -> h3 (k' = pi3, aliases h1) =====
  {
    float bv[2], gv[2], tv[2];
    #pragma unroll
    for (int nt = 0; nt < 2; nt++){
      int col = w*32 + nt*16 + c0;
      bv[nt] = eb3[e*128 + col]; gv[nt] = eg3[e*128 + col]; tv[nt] = ebt3[e*128 + col];
    }
    f32x4 acc[2][2];
    #pragma unroll
    for (int m = 0; m < 2; m++)
      #pragma unroll
      for (int nt = 0; nt < 2; nt++) acc[m][nt] = (f32x4){bv[nt],bv[nt],bv[nt],bv[nt]};
    #pragma unroll 2
    for (int kb = 0; kb < 8; kb++){
      bf16x8 a0 = *(const bf16x8*)(h2 + (0  + c0)*264 + kb*32 + q*8);
      bf16x8 a1 = *(const bf16x8*)(h2 + (16 + c0)*264 + kb*32 + q*8);
      #pragma unroll
      for (int nt = 0; nt < 2; nt++){
        int ntg = w*2 + nt;
        bf16x8 b = *(const bf16x8*)(W3p + ((size_t)((e*8 + ntg)*8 + kb)*64 + l)*8);
        acc[0][nt] = MFMA_BF16(a0, b, acc[0][nt], 0, 0, 0);
        acc[1][nt] = MFMA_BF16(a1, b, acc[1][nt], 0, 0, 0);
      }
    }
    float s[2][4] = {}, sq[2][4] = {};
    #pragma unroll
    for (int nt = 0; nt < 2; nt++)
      #pragma unroll
      for (int m = 0; m < 2; m++)
        #pragma unroll
        for (int r = 0; r < 4; r++){
          float v = acc[m][nt][r];
          s[m][r] += v; sq[m][r] += v*v;
        }
    #pragma unroll
    for (int m = 0; m < 2; m++)
      #pragma unroll
      for (int r = 0; r < 4; r++){
        float a = s[m][r], b = sq[m][r];
        #pragma unroll
        for (int off = 1; off < 16; off <<= 1){ a += __shfl_xor(a, off, 64); b += __shfl_xor(b, off, 64); }
        if (c0 == 0){ int row = m*16 + q*4 + r; redS[row*4 + w] = a; redQ[row*4 + w] = b; }
      }
    __syncthreads();
    if (tid < 32){
      float S = 0.f, Q = 0.f;
      #pragma unroll
      for (int i = 0; i < 4; i++){ S += redS[tid*4 + i]; Q += redQ[tid*4 + i]; }
      float mu = S * (1.0f/128.0f);
      float var = Q * (1.0f/128.0f) - mu*mu;
      muS[tid] = mu; rsS[tid] = rsqrtf(var + 1e-5f);
    }
    __syncthreads();
    #pragma unroll
    for (int m = 0; m < 2; m++)
      #pragma unroll
      for (int r = 0; r < 4; r++){
        int row = m*16 + q*4 + r;
        float mu = muS[row], rs = rsS[row];
        float v0 = silu_f((acc[m][0][r] - mu) * rs * gv[0] + tv[0]);
        float v1 = silu_f((acc[m][1][r] - mu) * rs * gv[1] + tv[1]);
        *(unsigned int*)(h3 + row*136 + w*32 + c0*2) = pk2(v0, v1);  // ds_write_b32, k' = w*32+c0*2+nt
      }
  }
  __syncthreads();

  // ===== stage 4: h3[32,128(pi3)] . w4p[e] + eb4 -> eo[b, e] =====
  {
    int row = tid >> 3, sub = tid & 7;
    bf16x8 v0 = *(const bf16x8*)(h3 + row*136 + sub*16);
    bf16x8 v1 = *(const bf16x8*)(h3 + row*136 + sub*16 + 8);
    float a = 0.f;
    #pragma unroll
    for (int j = 0; j < 8; j++) a += b2f((unsigned short)v0[j]) * w4p[e*128 + sub*16 + j];
    #pragma unroll
    for (int j = 0; j < 8; j++) a += b2f((unsigned short)v1[j]) * w4p[e*128 + sub*16 + 8 + j];
    a += __shfl_xor(a, 1, 64); a += __shfl_xor(a, 2, 64); a += __shfl_xor(a, 4, 64);
    if (sub == 0) eo[(size_t)(bt*32 + row)*8 + e] = a + eb4[e];
  }
}

// ---------------- fused gate path: one kernel, 32 rows/block, fp32, register-tiled ----------------
// N=128 layers: thread tile 4 rows x 4 cols; x-loads are half-wave-broadcast float4 from LDS;
// LN stats via 32-lane butterfly shuffle (no LDS round-trip).
template<int K, int PIN, int POUT, bool LN>
DEV void glayer128(const float* __restrict__ xs, const float* __restrict__ W, const float* __restrict__ b,
                   const float* __restrict__ g, const float* __restrict__ btv, float* __restrict__ ys, int tid)
{
  const int cg = tid & 31, rg = tid >> 5;
  const int col0 = cg * 4, row0 = rg * 4;
  float4 bv = *(const float4*)(b + col0);
  float acc[4][4];
  #pragma unroll
  for (int r = 0; r < 4; r++){ acc[r][0] = bv.x; acc[r][1] = bv.y; acc[r][2] = bv.z; acc[r][3] = bv.w; }
  for (int k = 0; k < K; k += 4){
    float4 x0 = *(const float4*)(xs + (row0+0)*PIN + k);
    float4 x1 = *(const float4*)(xs + (row0+1)*PIN + k);
    float4 x2 = *(const float4*)(xs + (row0+2)*PIN + k);
    float4 x3 = *(const float4*)(xs + (row0+3)*PIN + k);
    float4 w0 = *(const float4*)(W + (size_t)(k+0)*128 + col0);
    float4 w1 = *(const float4*)(W + (size_t)(k+1)*128 + col0);
    float4 w2 = *(const float4*)(W + (size_t)(k+2)*128 + col0);
    float4 w3 = *(const float4*)(W + (size_t)(k+3)*128 + col0);
    const float xr[4][4] = {{x0.x,x0.y,x0.z,x0.w},{x1.x,x1.y,x1.z,x1.w},{x2.x,x2.y,x2.z,x2.w},{x3.x,x3.y,x3.z,x3.w}};
    const float wr[4][4] = {{w0.x,w0.y,w0.z,w0.w},{w1.x,w1.y,w1.z,w1.w},{w2.x,w2.y,w2.z,w2.w},{w3.x,w3.y,w3.z,w3.w}};
    #pragma unroll
    for (int kk = 0; kk < 4; kk++)
      #pragma unroll
      for (int r = 0; r < 4; r++)
        #pragma unroll
        for (int c = 0; c < 4; c++) acc[r][c] += xr[r][kk] * wr[kk][c];
  }
  float mu[4], rs[4];
  if (LN){
    #pragma unroll
    for (int r = 0; r < 4; r++){
      float s = acc[r][0] + acc[r][1] + acc[r][2] + acc[r][3];
      float qq = acc[r][0]*acc[r][0] + acc[r][1]*acc[r][1] + acc[r][2]*acc[r][2] + acc[r][3]*acc[r][3];
      #pragma unroll
      for (int off = 1; off < 32; off <<= 1){ s += __shfl_xor(s, off, 64); qq += __shfl_xor(qq, off, 64); }
      float m = s * (1.0f/128.0f);
      mu[r] = m; rs[r] = rsqrtf(qq * (1.0f/128.0f) - m*m + 1e-5f);
    }
    float4 gv = *(const float4*)(g + col0);
    float4 tv = *(const float4*)(btv + col0);
    const float gr[4] = {gv.x, gv.y, gv.z, gv.w};
    const float tr[4] = {tv.x, tv.y, tv.z, tv.w};
    #pragma unroll
    for (int r = 0; r < 4; r++)
      #pragma unroll
      for (int c = 0; c < 4; c++) acc[r][c] = (acc[r][c] - mu[r]) * rs[r] * gr[c] + tr[c];
  }
  #pragma unroll
  for (int r = 0; r < 4; r++){
    float4 o;
    o.x = silu_f(acc[r][0]); o.y = silu_f(acc[r][1]); o.z = silu_f(acc[r][2]); o.w = silu_f(acc[r][3]);
    *(float4*)(ys + (row0+r)*POUT + col0) = o;
  }
}

// N=64, SiLU only: thread tile 2 rows x 4 cols
template<int K, int PIN, int POUT>
DEV void glayer64(const float* __restrict__ xs, const float* __restrict__ W, const float* __restrict__ b,
                  float* __restrict__ ys, int tid)
{
  const int cg = tid & 15, rg = tid >> 4;
  const int col0 = cg * 4, row0 = rg * 2;
  float4 bv = *(const float4*)(b + col0);
  float acc[2][4];
  #pragma unroll
  for (int r = 0; r < 2; r++){ acc[r][0] = bv.x; acc[r][1] = bv.y; acc[r][2] = bv.z; acc[r][3] = bv.w; }
  for (int k = 0; k < K; k += 4){
    float4 x0 = *(const float4*)(xs + (row0+0)*PIN + k);
    float4 x1 = *(const float4*)(xs + (row0+1)*PIN + k);
    float4 w0 = *(const float4*)(W + (size_t)(k+0)*64 + col0);
    float4 w1 = *(const float4*)(W + (size_t)(k+1)*64 + col0);
    float4 w2 = *(const float4*)(W + (size_t)(k+2)*64 + col0);
    float4 w3 = *(const float4*)(W + (size_t)(k+3)*64 + col0);
    const float xr[2][4] = {{x0.x,x0.y,x0.z,x0.w},{x1.x,x1.y,x1.z,x1.w}};
    const float wr[4][4] = {{w0.x,w0.y,w0.z,w0.w},{w1.x,w1.y,w1.z,w1.w},{w2.x,w2.y,w2.z,w2.w},{w3.x,w3.y,w3.z,w3.w}};
    #pragma unroll
    for (int kk = 0; kk < 4; kk++)
      #pragma unroll
      for (int r = 0; r < 2; r++)
        #pragma unroll
        for (int c = 0; c < 4; c++) acc[r][c] += xr[r][kk] * wr[kk][c];
  }
  #pragma unroll
  for (int r = 0; r < 2; r++){
    float4 o;
    o.x = silu_f(acc[r][0]); o.y = silu_f(acc[r][1]); o.z = silu_f(acc[r][2]); o.w = silu_f(acc[r][3]);
    *(float4*)(ys + (row0+r)*POUT + col0) = o;
  }
}

__global__ __launch_bounds__(256, 4)
void gate_fused(const float* __restrict__ gf,
                const float* __restrict__ bW1, const float* __restrict__ bb1, const float* __restrict__ bg1, const float* __restrict__ bbt1,
                const float* __restrict__ bW2, const float* __restrict__ bb2, const float* __restrict__ bg2, const float* __restrict__ bbt2,
                const float* __restrict__ encW1, const float* __restrict__ encb1, const float* __restrict__ encW2, const float* __restrict__ encb2,
                const float* __restrict__ gW1, const float* __restrict__ gb1, const float* __restrict__ gg1v, const float* __restrict__ gbt1,
                const float* __restrict__ gW2, const float* __restrict__ gb2, const float* __restrict__ gW3, const float* __restrict__ gb3,
                float* __restrict__ out_z, float* __restrict__ out_logits, float* __restrict__ out_gates)
{
  const int tid = threadIdx.x;
  const int row0 = blockIdx.x * 32;
  __shared__ __align__(16) float xa[32 * 148];   // holds up to K=144
  __shared__ __align__(16) float xb[32 * 132];

  // load gate_features [32,64]
  for (int idx = tid; idx < 32*64; idx += 256){
    int r = idx >> 6, k = idx & 63;
    xa[r*148 + k] = gf[(size_t)(row0 + r)*64 + k];
  }
  __syncthreads();
  glayer128<64, 148, 132, true>(xa, bW1, bb1, bg1, bbt1, xb, tid);     // h1 -> xb
  __syncthreads();
  glayer128<128, 132, 148, true>(xb, bW2, bb2, bg2, bbt2, xa, tid);    // h2 -> xa[0..127]
  __syncthreads();
  glayer64<128, 148, 132>(xa, encW1, encb1, xb, tid);                  // enc1 -> xb[0..63]
  __syncthreads();
  { // enc2: xb[32,64] @ encW2[64,16] -> z; write out_z and xa cols 128..143
    int col = tid & 15, rr = tid >> 4;           // rr 0..15 -> rows rr*2, rr*2+1
    float a0 = encb2[col], a1 = a0;
    for (int k = 0; k < 64; k++){
      float wv = encW2[k*16 + col];
      a0 += xb[(rr*2+0)*132 + k] * wv;
      a1 += xb[(rr*2+1)*132 + k] * wv;
    }
    out_z[(size_t)(row0 + rr*2+0)*16 + col] = a0;
    out_z[(size_t)(row0 + rr*2+1)*16 + col] = a1;
    xa[(rr*2+0)*148 + 128 + col] = a0;
    xa[(rr*2+1)*148 + 128 + col] = a1;
  }
  __syncthreads();
  glayer128<144, 148, 132, true>(xa, gW1, gb1, gg1v, gbt1, xb, tid);   // gating h -> xb
  __syncthreads();
  glayer64<128, 132, 148>(xb, gW2, gb2, xa, tid);                      // -> xa[0..63]
  __syncthreads();
  { // g3: xa[32,64] @ gW3[64,8] -> logits; softmax -> gates
    int col = tid & 7, rr = tid >> 3;            // rr 0..31
    float a = gb3[col];
    for (int k = 0; k < 64; k++) a += xa[rr*148 + k] * gW3[k*8 + col];
    out_logits[(size_t)(row0 + rr)*8 + col] = a;
    float m = a;
    m = fmaxf(m, __shfl_xor(m, 1, 64));
    m = fmaxf(m, __shfl_xor(m, 2, 64));
    m = fmaxf(m, __shfl_xor(m, 4, 64));
    float ex = __expf(a - m);
    float s = ex;
    s += __shfl_xor(s, 1, 64); s += __shfl_xor(s, 2, 64); s += __shfl_xor(s, 4, 64);
    out_gates[(size_t)(row0 + rr)*8 + col] = ex / s;
  }
}

// ---------------- final mix: mixed[b] = sum_e eo[b,e]*gates[b,e] ----------------
__global__ __launch_bounds__(256) void mix_kernel(const float* __restrict__ eo, const float* __restrict__ gates,
                                                  float* __restrict__ mixed){
  int t = blockIdx.x * 256 + threadIdx.x;
  if (t < 32768){
    const float4* a = (const float4*)(eo + (size_t)t*8);
    const float4* gg = (const float4*)(gates + (size_t)t*8);
    float4 a0 = a[0], a1 = a[1], g0 = gg[0], g1 = gg[1];
    mixed[t] = a0.x*g0.x + a0.y*g0.y + a0.z*g0.z + a0.w*g0.w
             + a1.x*g1.x + a1.y*g1.y + a1.z*g1.z + a1.w*g1.w;
  }
}

extern "C" void kernel_launch(void* const* d_in, const int* in_sizes, int n_in,
                              void* d_out, int out_size, void* d_ws, size_t ws_size,
                              hipStream_t stream)
{
  if (n_in < 36 || in_sizes[0] != 32768*128 || out_size < 1081344) return;

  const float* expert_features = (const float*)d_in[0];
  const float* gate_features   = (const float*)d_in[1];
  const float* eW1 = (const float*)d_in[2];
  const float* eb1 = (const float*)d_in[3];
  const float* eg1 = (const float*)d_in[4];
  const float* ebt1= (const float*)d_in[5];
  const float* eW2 = (const float*)d_in[6];
  const float* eb2 = (const float*)d_in[7];
  const float* eg2 = (const float*)d_in[8];
  const float* ebt2= (const float*)d_in[9];
  const float* eW3 = (const float*)d_in[10];
  const float* eb3 = (const float*)d_in[11];
  const float* eg3 = (const float*)d_in[12];
  const float* ebt3= (const float*)d_in[13];
  const float* eW4 = (const float*)d_in[14];
  const float* eb4 = (const float*)d_in[15];
  const float* bW1 = (const float*)d_in[16];
  const float* bb1 = (const float*)d_in[17];
  const float* bg1 = (const float*)d_in[18];
  const float* bbt1= (const float*)d_in[19];
  const float* bW2 = (const float*)d_in[20];
  const float* bb2 = (const float*)d_in[21];
  const float* bg2 = (const float*)d_in[22];
  const float* bbt2= (const float*)d_in[23];
  const float* encW1 = (const float*)d_in[24];
  const float* encb1 = (const float*)d_in[25];
  const float* encW2 = (const float*)d_in[26];
  const float* encb2 = (const float*)d_in[27];
  const float* gW1 = (const float*)d_in[28];
  const float* gb1 = (const float*)d_in[29];
  const float* gg1 = (const float*)d_in[30];
  const float* gbt1= (const float*)d_in[31];
  const float* gW2 = (const float*)d_in[32];
  const float* gb2 = (const float*)d_in[33];
  const float* gW3 = (const float*)d_in[34];
  const float* gb3 = (const float*)d_in[35];

  float* out        = (float*)d_out;
  float* out_mixed  = out;                 // [B]
  float* out_z      = out + 32768;         // [B,16]
  float* out_logits = out + 557056;        // [B,8]
  float* out_gates  = out + 819200;        // [B,8]

  char* ws = (char*)d_ws;
  size_t off = 0;
  auto walloc = [&](size_t bytes) -> char* { char* p = ws + off; off += (bytes + 255) & ~(size_t)255; return p; };
  unsigned short* Xp  = (unsigned short*)walloc((size_t)4194304 * 2);  // packed X, bf16
  unsigned short* W1p = (unsigned short*)walloc((size_t)524288  * 2);
  unsigned short* W2p = (unsigned short*)walloc((size_t)1048576 * 2);
  unsigned short* W3p = (unsigned short*)walloc((size_t)262144  * 2);
  float*          w4p = (float*)walloc((size_t)1024 * 4);
  float*          eo  = (float*)walloc((size_t)262144 * 4);            // expert outputs [B,8]
  if (off > ws_size) return;  // workspace too small -> clean failure signal

  // --- pack ---
  pack_x_kernel<<<2048, 256, 0, stream>>>(expert_features, Xp);
  pack_w_kernel<<< 900, 256, 0, stream>>>(eW1, eW2, eW3, eW4, W1p, W2p, W3p, w4p);

  // --- gate path (fused, fp32) ---
  gate_fused<<<1024, 256, 0, stream>>>(gate_features,
                                       bW1, bb1, bg1, bbt1, bW2, bb2, bg2, bbt2,
                                       encW1, encb1, encW2, encb2,
                                       gW1, gb1, gg1, gbt1, gW2, gb2, gW3, gb3,
                                       out_z, out_logits, out_gates);

  // --- fused experts (bf16 MFMA) ---
  expert_kernel<<<dim3(1024, 8), 256, 0, stream>>>(Xp, W1p, W2p, W3p, w4p,
                                                   eb1, eg1, ebt1, eb2, eg2, ebt2, eb3, eg3, ebt3,
                                                   eb4, eo);

  // --- mix ---
  mix_kernel<<<128, 256, 0, stream>>>(eo, out_gates, out_mixed);
}

// Round 5
// 473.629 us; speedup vs baseline: 1.3658x; 1.0569x over previous
//
#include <hip/hip_runtime.h>
#include <hip/hip_bf16.h>

// LatentSensorMoE: fused bf16-MFMA expert MLPs + fused fp32 gate path.
// B=32768, EIN=128, E=8, experts 128->512->256->128->1 (LN+SiLU per hidden),
// gate: 64->128(LN,SiLU)->128(LN,SiLU); enc 128->64(SiLU)->16; gating 144->128(LN,SiLU)->64(SiLU)->8->softmax.
// Outputs (fp32, concat): mixed[B] | z[B,16] | logits[B,8] | gates[B,8]
//
// R5 bisection: round-2 PASSING kernel verbatim (32-row gate, bias-in-C-init,
// muS/rsS, IEEE silu, shfl_xor) + ONLY the expert structural pair under test:
// {h2=h1, h3=h1+32*264, __launch_bounds__(256,4)}.

typedef __attribute__((ext_vector_type(8))) short bf16x8;   // 8 bf16 = 4 VGPR (MFMA frag)
typedef __attribute__((ext_vector_type(4))) short bf16x4;
typedef __attribute__((ext_vector_type(4))) float f32x4;

#define DEV static __device__ __forceinline__

DEV float b2f(unsigned short u){ union { unsigned int i; float f; } x; x.i = ((unsigned int)u) << 16; return x.f; }
DEV unsigned short f2b(float f){
  union { float f; unsigned int i; } x; x.f = f;
  return (unsigned short)((x.i + 0x7fffu + ((x.i >> 16) & 1u)) >> 16);  // RNE
}
DEV unsigned int pk2(float a, float b){
  __hip_bfloat162 h = __float22bfloat162_rn(make_float2(a, b));        // v_cvt_pk_bf16_f32
  union { __hip_bfloat162 h; unsigned int u; } u; u.h = h; return u.u;
}
DEV float silu_f(float v){ return v / (1.0f + __expf(-v)); }

// ---------------- pack kernels: fp32 -> bf16 MFMA fragment layouts ----------------
// A-frag (16x16x32): lane l holds A[m=l&15][k=(l>>4)*8+j], j=0..7  -> 16B/lane contiguous
// B-frag:            lane l holds B[k=(l>>4)*8+j][n=l&15]
// Stage s output is written to LDS in permuted k' order; W(s+1) k-dim pre-permuted to match:
//  pi1: col c=(w*128+nt*16+c0) -> k' = w*128 + c0*8 + nt   (nt<8)
//  pi2: col c=(w*64 +nt*16+c0) -> k' = w*64  + c0*4 + nt   (nt<4)
//  pi3: col c=(w*32 +nt*16+c0) -> k' = w*32  + c0*2 + nt   (nt<2)

__global__ __launch_bounds__(256) void pack_x_kernel(const float* __restrict__ X, unsigned short* __restrict__ Xp){
  int t = blockIdx.x * 256 + threadIdx.x;          // [0, 2048*4*64)
  int l = t & 63, kb = (t >> 6) & 3, mtg = t >> 8; // mtg: 16-row tile id [0,2048)
  int row = mtg * 16 + (l & 15);
  int k0  = kb * 32 + (l >> 4) * 8;
  const float* src = X + (size_t)row * 128 + k0;
  bf16x8 o;
  #pragma unroll
  for (int j = 0; j < 8; j++) o[j] = (short)f2b(src[j]);
  *(bf16x8*)(Xp + (size_t)t * 8) = o;
}

// combined weight pack: blocks [0,256)=W1, [256,768)=W2, [768,896)=W3, [896,900)=w4
__global__ __launch_bounds__(256) void pack_w_kernel(const float* __restrict__ eW1, const float* __restrict__ eW2,
                                                     const float* __restrict__ eW3, const float* __restrict__ eW4,
                                                     unsigned short* __restrict__ W1p, unsigned short* __restrict__ W2p,
                                                     unsigned short* __restrict__ W3p, float* __restrict__ w4p){
  int b = blockIdx.x;
  if (b < 256){
    int t = b * 256 + threadIdx.x;                 // [0, 65536)
    int l = t & 63, kb = (t >> 6) & 3, ntg = (t >> 8) & 31, e = t >> 13;
    int q = l >> 4, c0 = l & 15, n = ntg * 16 + c0;
    bf16x8 o;
    #pragma unroll
    for (int j = 0; j < 8; j++){ int k = kb*32 + q*8 + j; o[j] = (short)f2b(eW1[((size_t)e*128 + k)*512 + n]); }
    *(bf16x8*)(W1p + (size_t)t * 8) = o;
  } else if (b < 768){
    int t = (b - 256) * 256 + threadIdx.x;         // [0, 131072)
    int l = t & 63, kb = (t >> 6) & 15, ntg = (t >> 10) & 15, e = t >> 14;
    int q = l >> 4, c0 = l & 15, n = ntg * 16 + c0;
    bf16x8 o;
    #pragma unroll
    for (int j = 0; j < 8; j++){
      int kp = kb*32 + q*8 + j;                                        // k' in pi1 space
      int c = (kp >> 7) * 128 + (kp & 7) * 16 + ((kp >> 3) & 15);      // pi1^-1
      o[j] = (short)f2b(eW2[((size_t)e*512 + c)*256 + n]);
    }
    *(bf16x8*)(W2p + (size_t)t * 8) = o;
  } else if (b < 896){
    int t = (b - 768) * 256 + threadIdx.x;         // [0, 32768)
    int l = t & 63, kb = (t >> 6) & 7, ntg = (t >> 9) & 7, e = t >> 12;
    int q = l >> 4, c0 = l & 15, n = ntg * 16 + c0;
    bf16x8 o;
    #pragma unroll
    for (int j = 0; j < 8; j++){
      int kp = kb*32 + q*8 + j;                                        // k' in pi2 space
      int c = (kp >> 6) * 64 + (kp & 3) * 16 + ((kp >> 2) & 15);       // pi2^-1
      o[j] = (short)f2b(eW3[((size_t)e*256 + c)*128 + n]);
    }
    *(bf16x8*)(W3p + (size_t)t * 8) = o;
  } else {
    int t = (b - 896) * 256 + threadIdx.x;
    if (t < 1024){
      int e = t >> 7, kp = t & 127;
      int c = (kp >> 5) * 32 + (kp & 1) * 16 + ((kp >> 1) & 15);       // pi3^-1
      w4p[t] = eW4[e * 128 + c];
    }
  }
}

// ---------------- fused expert kernel: 32 rows x 1 expert per workgroup ----------------
// grid (1024, 8), 256 threads (4 waves). Waves split the N dim of each layer.
// UNDER TEST THIS ROUND: h2 aliases h1[0,16896)B, h3 at [16896,25600)B, launch_bounds(256,4).
// Every read of the dead buffer completes before the reduction barrier that precedes
// the overwriting epilogue. 34.6 KB LDS -> 4 wg/CU.
#define MFMA_BF16 __builtin_amdgcn_mfma_f32_16x16x32_bf16

__global__ __launch_bounds__(256, 4)
void expert_kernel(const unsigned short* __restrict__ Xp,
                   const unsigned short* __restrict__ W1p,
                   const unsigned short* __restrict__ W2p,
                   const unsigned short* __restrict__ W3p,
                   const float* __restrict__ w4p,
                   const float* __restrict__ eb1, const float* __restrict__ eg1, const float* __restrict__ ebt1,
                   const float* __restrict__ eb2, const float* __restrict__ eg2, const float* __restrict__ ebt2,
                   const float* __restrict__ eb3, const float* __restrict__ eg3, const float* __restrict__ ebt3,
                   const float* __restrict__ eb4, float* __restrict__ eo)
{
  const int e = blockIdx.y, bt = blockIdx.x;
  const int tid = threadIdx.x;
  const int w = tid >> 6, l = tid & 63;
  const int q = l >> 4, c0 = l & 15;

  __shared__ __align__(16) unsigned short h1[32 * 520];  // 33280 B
  __shared__ float redS[32 * 4];
  __shared__ float redQ[32 * 4];
  __shared__ float muS[32];
  __shared__ float rsS[32];
  unsigned short* h2 = h1;                 // [0, 16896) B
  unsigned short* h3 = h1 + 32 * 264;      // [16896, 25600) B

  // ===== stage 1: X[32,128] @ W1[128,512], +b (as C-init), LN, SiLU -> h1 (k' = pi1) =====
  {
    float bv[8], gv[8], tv[8];
    #pragma unroll
    for (int nt = 0; nt < 8; nt++){
      int col = w*128 + nt*16 + c0;
      bv[nt] = eb1[e*512 + col]; gv[nt] = eg1[e*512 + col]; tv[nt] = ebt1[e*512 + col];
    }
    f32x4 acc[2][8];
    #pragma unroll
    for (int m = 0; m < 2; m++)
      #pragma unroll
      for (int nt = 0; nt < 8; nt++) acc[m][nt] = (f32x4){bv[nt],bv[nt],bv[nt],bv[nt]};
    #pragma unroll
    for (int kb = 0; kb < 4; kb++){
      bf16x8 a0 = *(const bf16x8*)(Xp + ((size_t)((bt*2 + 0)*4 + kb)*64 + l)*8);
      bf16x8 a1 = *(const bf16x8*)(Xp + ((size_t)((bt*2 + 1)*4 + kb)*64 + l)*8);
      #pragma unroll
      for (int nt = 0; nt < 8; nt++){
        int ntg = w*8 + nt;
        bf16x8 b = *(const bf16x8*)(W1p + ((size_t)((e*32 + ntg)*4 + kb)*64 + l)*8);
        acc[0][nt] = MFMA_BF16(a0, b, acc[0][nt], 0, 0, 0);
        acc[1][nt] = MFMA_BF16(a1, b, acc[1][nt], 0, 0, 0);
      }
    }
    float s[2][4] = {}, sq[2][4] = {};
    #pragma unroll
    for (int nt = 0; nt < 8; nt++)
      #pragma unroll
      for (int m = 0; m < 2; m++)
        #pragma unroll
        for (int r = 0; r < 4; r++){
          float v = acc[m][nt][r];
          s[m][r] += v; sq[m][r] += v*v;
        }
    #pragma unroll
    for (int m = 0; m < 2; m++)
      #pragma unroll
      for (int r = 0; r < 4; r++){
        float a = s[m][r], b = sq[m][r];
        #pragma unroll
        for (int off = 1; off < 16; off <<= 1){ a += __shfl_xor(a, off, 64); b += __shfl_xor(b, off, 64); }
        if (c0 == 0){ int row = m*16 + q*4 + r; redS[row*4 + w] = a; redQ[row*4 + w] = b; }
      }
    __syncthreads();
    if (tid < 32){
      float S = 0.f, Q = 0.f;
      #pragma unroll
      for (int i = 0; i < 4; i++){ S += redS[tid*4 + i]; Q += redQ[tid*4 + i]; }
      float mu = S * (1.0f/512.0f);
      float var = Q * (1.0f/512.0f) - mu*mu;
      muS[tid] = mu; rsS[tid] = rsqrtf(var + 1e-5f);
    }
    __syncthreads();
    #pragma unroll
    for (int m = 0; m < 2; m++)
      #pragma unroll
      for (int r = 0; r < 4; r++){
        int row = m*16 + q*4 + r;
        float mu = muS[row], rs = rsS[row];
        float v[8];
        #pragma unroll
        for (int nt = 0; nt < 8; nt++) v[nt] = silu_f((acc[m][nt][r] - mu) * rs * gv[nt] + tv[nt]);
        uint4 pk;
        pk.x = pk2(v[0], v[1]); pk.y = pk2(v[2], v[3]); pk.z = pk2(v[4], v[5]); pk.w = pk2(v[6], v[7]);
        *(uint4*)(h1 + row*520 + w*128 + c0*8) = pk;   // ds_write_b128, k' = w*128+c0*8+nt
      }
  }
  __syncthreads();

  // ===== stage 2: h1[32,512(pi1)] @ W2p, +b, LN, SiLU -> h2 (k' = pi2, aliases h1) =====
  {
    float bv[4], gv[4], tv[4];
    #pragma unroll
    for (int nt = 0; nt < 4; nt++){
      int col = w*64 + nt*16 + c0;
      bv[nt] = eb2[e*256 + col]; gv[nt] = eg2[e*256 + col]; tv[nt] = ebt2[e*256 + col];
    }
    f32x4 acc[2][4];
    #pragma unroll
    for (int m = 0; m < 2; m++)
      #pragma unroll
      for (int nt = 0; nt < 4; nt++) acc[m][nt] = (f32x4){bv[nt],bv[nt],bv[nt],bv[nt]};
    #pragma unroll 2
    for (int kb = 0; kb < 16; kb++){
      bf16x8 a0 = *(const bf16x8*)(h1 + (0  + c0)*520 + kb*32 + q*8);
      bf16x8 a1 = *(const bf16x8*)(h1 + (16 + c0)*520 + kb*32 + q*8);
      #pragma unroll
      for (int nt = 0; nt < 4; nt++){
        int ntg = w*4 + nt;
        bf16x8 b = *(const bf16x8*)(W2p + ((size_t)((e*16 + ntg)*16 + kb)*64 + l)*8);
        acc[0][nt] = MFMA_BF16(a0, b, acc[0][nt], 0, 0, 0);
        acc[1][nt] = MFMA_BF16(a1, b, acc[1][nt], 0, 0, 0);
      }
    }
    float s[2][4] = {}, sq[2][4] = {};
    #pragma unroll
    for (int nt = 0; nt < 4; nt++)
      #pragma unroll
      for (int m = 0; m < 2; m++)
        #pragma unroll
        for (int r = 0; r < 4; r++){
          float v = acc[m][nt][r];
          s[m][r] += v; sq[m][r] += v*v;
        }
    #pragma unroll
    for (int m = 0; m < 2; m++)
      #pragma unroll
      for (int r = 0; r < 4; r++){
        float a = s[m][r], b = sq[m][r];
        #pragma unroll
        for (int off = 1; off < 16; off <<= 1){ a += __shfl_xor(a, off, 64); b += __shfl_xor(b, off, 64); }
        if (c0 == 0){ int row = m*16 + q*4 + r; redS[row*4 + w] = a; redQ[row*4 + w] = b; }
      }
    __syncthreads();   // all stage-2 k-loop reads of h1 complete here -> h2 may overwrite h1
    if (tid < 32){
      float S = 0.f, Q = 0.f;
      #pragma unroll
      for (int i = 0; i < 4; i++){ S += redS[tid*4 + i]; Q += redQ[tid*4 + i]; }
      float mu = S * (1.0f/256.0f);
      float var = Q * (1.0f/256.0f) - mu*mu;
      muS[tid] = mu; rsS[tid] = rsqrtf(var + 1e-5f);
    }
    __syncthreads();
    #pragma unroll
    for (int m = 0; m < 2; m++)
      #pragma unroll
      for (int r = 0; r < 4; r++){
        int row = m*16 + q*4 + r;
        float mu = muS[row], rs = rsS[row];
        float v[4];
        #pragma unroll
        for (int nt = 0; nt < 4; nt++) v[nt] = silu_f((acc[m][nt][r] - mu) * rs * gv[nt] + tv[nt]);
        uint2 pk; pk.x = pk2(v[0], v[1]); pk.y = pk2(v[2], v[3]);
        *(uint2*)(h2 + row*264 + w*64 + c0*4) = pk;    // ds_write_b64, k' = w*64+c0*4+nt
      }
  }
  __syncthreads();

  // ===== stage 3: h2[32,256(pi2)] @ W3p, +b, LN, SiLU -> h3 (k' = pi3) =====
  {
    float bv[2], gv[2], tv[2];
    #pragma unroll
    for (int nt = 0; nt < 2; nt++){
      int col = w*32 + nt*16 + c0;
      bv[nt] = eb3[e*128 + col]; gv[nt] = eg3[e*128 + col]; tv[nt] = ebt3[e*128 + col];
    }
    f32x4 acc[2][2];
    #pragma unroll
    for (int m = 0; m < 2; m++)
      #pragma unroll
      for (int nt = 0; nt < 2; nt++) acc[m][nt] = (f32x4){bv[nt],bv[nt],bv[nt],bv[nt]};
    #pragma unroll 2
    for (int kb = 0; kb < 8; kb++){
      bf16x8 a0 = *(const bf16x8*)(h2 + (0  + c0)*264 + kb*32 + q*8);
      bf16x8 a1 = *(const bf16x8*)(h2 + (16 + c0)*264 + kb*32 + q*8);
      #pragma unroll
      for (int nt = 0; nt < 2; nt++){
        int ntg = w*2 + nt;
        bf16x8 b = *(const bf16x8*)(W3p + ((size_t)((e*8 + ntg)*8 + kb)*64 + l)*8);
        acc[0][nt] = MFMA_BF16(a0, b, acc[0][nt], 0, 0, 0);
        acc[1][nt] = MFMA_BF16(a1, b, acc[1][nt], 0, 0, 0);
      }
    }
    float s[2][4] = {}, sq[2][4] = {};
    #pragma unroll
    for (int nt = 0; nt < 2; nt++)
      #pragma unroll
      for (int m = 0; m < 2; m++)
        #pragma unroll
        for (int r = 0; r < 4; r++){
          float v = acc[m][nt][r];
          s[m][r] += v; sq[m][r] += v*v;
        }
    #pragma unroll
    for (int m = 0; m < 2; m++)
      #pragma unroll
      for (int r = 0; r < 4; r++){
        float a = s[m][r], b = sq[m][r];
        #pragma unroll
        for (int off = 1; off < 16; off <<= 1){ a += __shfl_xor(a, off, 64); b += __shfl_xor(b, off, 64); }
        if (c0 == 0){ int row = m*16 + q*4 + r; redS[row*4 + w] = a; redQ[row*4 + w] = b; }
      }
    __syncthreads();   // all stage-3 k-loop reads of h2 complete here
    if (tid < 32){
      float S = 0.f, Q = 0.f;
      #pragma unroll
      for (int i = 0; i < 4; i++){ S += redS[tid*4 + i]; Q += redQ[tid*4 + i]; }
      float mu = S * (1.0f/128.0f);
      float var = Q * (1.0f/128.0f) - mu*mu;
      muS[tid] = mu; rsS[tid] = rsqrtf(var + 1e-5f);
    }
    __syncthreads();
    #pragma unroll
    for (int m = 0; m < 2; m++)
      #pragma unroll
      for (int r = 0; r < 4; r++){
        int row = m*16 + q*4 + r;
        float mu = muS[row], rs = rsS[row];
        float v0 = silu_f((acc[m][0][r] - mu) * rs * gv[0] + tv[0]);
        float v1 = silu_f((acc[m][1][r] - mu) * rs * gv[1] + tv[1]);
        *(unsigned int*)(h3 + row*136 + w*32 + c0*2) = pk2(v0, v1);  // ds_write_b32, k' = w*32+c0*2+nt
      }
  }
  __syncthreads();

  // ===== stage 4: h3[32,128(pi3)] . w4p[e] + eb4 -> eo[b, e] =====
  {
    int row = tid >> 3, sub = tid & 7;
    bf16x8 v0 = *(const bf16x8*)(h3 + row*136 + sub*16);
    bf16x8 v1 = *(const bf16x8*)(h3 + row*136 + sub*16 + 8);
    float a = 0.f;
    #pragma unroll
    for (int j = 0; j < 8; j++) a += b2f((unsigned short)v0[j]) * w4p[e*128 + sub*16 + j];
    #pragma unroll
    for (int j = 0; j < 8; j++) a += b2f((unsigned short)v1[j]) * w4p[e*128 + sub*16 + 8 + j];
    a += __shfl_xor(a, 1, 64); a += __shfl_xor(a, 2, 64); a += __shfl_xor(a, 4, 64);
    if (sub == 0) eo[(size_t)(bt*32 + row)*8 + e] = a + eb4[e];
  }
}

// ---------------- fused gate path (round-2 VERBATIM): 32 rows/block, fp32 ----------------
// N=128 layer: thread tile 4 rows x 4 cols
template<int K, int PIN, int POUT, bool LN>
DEV void glayer128(const float* __restrict__ xs, const float* __restrict__ W, const float* __restrict__ b,
                   const float* __restrict__ g, const float* __restrict__ btv, float* __restrict__ ys, int tid)
{
  const int cg = tid & 31, rg = tid >> 5;
  const int col0 = cg * 4, row0 = rg * 4;
  float4 bv = *(const float4*)(b + col0);
  float acc[4][4];
  #pragma unroll
  for (int r = 0; r < 4; r++){ acc[r][0] = bv.x; acc[r][1] = bv.y; acc[r][2] = bv.z; acc[r][3] = bv.w; }
  for (int k = 0; k < K; k += 4){
    float4 x0 = *(const float4*)(xs + (row0+0)*PIN + k);
    float4 x1 = *(const float4*)(xs + (row0+1)*PIN + k);
    float4 x2 = *(const float4*)(xs + (row0+2)*PIN + k);
    float4 x3 = *(const float4*)(xs + (row0+3)*PIN + k);
    float4 w0 = *(const float4*)(W + (size_t)(k+0)*128 + col0);
    float4 w1 = *(const float4*)(W + (size_t)(k+1)*128 + col0);
    float4 w2 = *(const float4*)(W + (size_t)(k+2)*128 + col0);
    float4 w3 = *(const float4*)(W + (size_t)(k+3)*128 + col0);
    const float xr[4][4] = {{x0.x,x0.y,x0.z,x0.w},{x1.x,x1.y,x1.z,x1.w},{x2.x,x2.y,x2.z,x2.w},{x3.x,x3.y,x3.z,x3.w}};
    const float wr[4][4] = {{w0.x,w0.y,w0.z,w0.w},{w1.x,w1.y,w1.z,w1.w},{w2.x,w2.y,w2.z,w2.w},{w3.x,w3.y,w3.z,w3.w}};
    #pragma unroll
    for (int kk = 0; kk < 4; kk++)
      #pragma unroll
      for (int r = 0; r < 4; r++)
        #pragma unroll
        for (int c = 0; c < 4; c++) acc[r][c] += xr[r][kk] * wr[kk][c];
  }
  float mu[4], rs[4];
  if (LN){
    #pragma unroll
    for (int r = 0; r < 4; r++){
      float s = acc[r][0] + acc[r][1] + acc[r][2] + acc[r][3];
      float qq = acc[r][0]*acc[r][0] + acc[r][1]*acc[r][1] + acc[r][2]*acc[r][2] + acc[r][3]*acc[r][3];
      #pragma unroll
      for (int off = 1; off < 32; off <<= 1){ s += __shfl_xor(s, off, 64); qq += __shfl_xor(qq, off, 64); }
      float m = s * (1.0f/128.0f);
      mu[r] = m; rs[r] = rsqrtf(qq * (1.0f/128.0f) - m*m + 1e-5f);
    }
    float4 gv = *(const float4*)(g + col0);
    float4 tv = *(const float4*)(btv + col0);
    const float gr[4] = {gv.x, gv.y, gv.z, gv.w};
    const float tr[4] = {tv.x, tv.y, tv.z, tv.w};
    #pragma unroll
    for (int r = 0; r < 4; r++)
      #pragma unroll
      for (int c = 0; c < 4; c++) acc[r][c] = (acc[r][c] - mu[r]) * rs[r] * gr[c] + tr[c];
  }
  #pragma unroll
  for (int r = 0; r < 4; r++){
    float4 o;
    o.x = silu_f(acc[r][0]); o.y = silu_f(acc[r][1]); o.z = silu_f(acc[r][2]); o.w = silu_f(acc[r][3]);
    *(float4*)(ys + (row0+r)*POUT + col0) = o;
  }
}

// N=64, SiLU only: thread tile 2 rows x 4 cols
template<int K, int PIN, int POUT>
DEV void glayer64(const float* __restrict__ xs, const float* __restrict__ W, const float* __restrict__ b,
                  float* __restrict__ ys, int tid)
{
  const int cg = tid & 15, rg = tid >> 4;
  const int col0 = cg * 4, row0 = rg * 2;
  float4 bv = *(const float4*)(b + col0);
  float acc[2][4];
  #pragma unroll
  for (int r = 0; r < 2; r++){ acc[r][0] = bv.x; acc[r][1] = bv.y; acc[r][2] = bv.z; acc[r][3] = bv.w; }
  for (int k = 0; k < K; k += 4){
    float4 x0 = *(const float4*)(xs + (row0+0)*PIN + k);
    float4 x1 = *(const float4*)(xs + (row0+1)*PIN + k);
    float4 w0 = *(const float4*)(W + (size_t)(k+0)*64 + col0);
    float4 w1 = *(const float4*)(W + (size_t)(k+1)*64 + col0);
    float4 w2 = *(const float4*)(W + (size_t)(k+2)*64 + col0);
    float4 w3 = *(const float4*)(W + (size_t)(k+3)*64 + col0);
    const float xr[2][4] = {{x0.x,x0.y,x0.z,x0.w},{x1.x,x1.y,x1.z,x1.w}};
    const float wr[4][4] = {{w0.x,w0.y,w0.z,w0.w},{w1.x,w1.y,w1.z,w1.w},{w2.x,w2.y,w2.z,w2.w},{w3.x,w3.y,w3.z,w3.w}};
    #pragma unroll
    for (int kk = 0; kk < 4; kk++)
      #pragma unroll
      for (int r = 0; r < 2; r++)
        #pragma unroll
        for (int c = 0; c < 4; c++) acc[r][c] += xr[r][kk] * wr[kk][c];
  }
  #pragma unroll
  for (int r = 0; r < 2; r++){
    float4 o;
    o.x = silu_f(acc[r][0]); o.y = silu_f(acc[r][1]); o.z = silu_f(acc[r][2]); o.w = silu_f(acc[r][3]);
    *(float4*)(ys + (row0+r)*POUT + col0) = o;
  }
}

__global__ __launch_bounds__(256, 4)
void gate_fused(const float* __restrict__ gf,
                const float* __restrict__ bW1, const float* __restrict__ bb1, const float* __restrict__ bg1, const float* __restrict__ bbt1,
                const float* __restrict__ bW2, const float* __restrict__ bb2, const float* __restrict__ bg2, const float* __restrict__ bbt2,
                const float* __restrict__ encW1, const float* __restrict__ encb1, const float* __restrict__ encW2, const float* __restrict__ encb2,
                const float* __restrict__ gW1, const float* __restrict__ gb1, const float* __restrict__ gg1v, const float* __restrict__ gbt1,
                const float* __restrict__ gW2, const float* __restrict__ gb2, const float* __restrict__ gW3, const float* __restrict__ gb3,
                float* __restrict__ out_z, float* __restrict__ out_logits, float* __restrict__ out_gates)
{
  const int tid = threadIdx.x;
  const int row0 = blockIdx.x * 32;
  __shared__ __align__(16) float xa[32 * 148];   // holds up to K=144
  __shared__ __align__(16) float xb[32 * 132];

  // load gate_features [32,64]
  for (int idx = tid; idx < 32*64; idx += 256){
    int r = idx >> 6, k = idx & 63;
    xa[r*148 + k] = gf[(size_t)(row0 + r)*64 + k];
  }
  __syncthreads();
  glayer128<64, 148, 132, true>(xa, bW1, bb1, bg1, bbt1, xb, tid);     // h1 -> xb
  __syncthreads();
  glayer128<128, 132, 148, true>(xb, bW2, bb2, bg2, bbt2, xa, tid);    // h2 -> xa[0..127]
  __syncthreads();
  glayer64<128, 148, 132>(xa, encW1, encb1, xb, tid);                  // enc1 -> xb[0..63]
  __syncthreads();
  { // enc2: xb[32,64] @ encW2[64,16] -> z; write out_z and xa cols 128..143
    int col = tid & 15, rr = tid >> 4;           // rr 0..15 -> rows rr*2, rr*2+1
    float a0 = encb2[col], a1 = a0;
    for (int k = 0; k < 64; k++){
      float wv = encW2[k*16 + col];
      a0 += xb[(rr*2+0)*132 + k] * wv;
      a1 += xb[(rr*2+1)*132 + k] * wv;
    }
    out_z[(size_t)(row0 + rr*2+0)*16 + col] = a0;
    out_z[(size_t)(row0 + rr*2+1)*16 + col] = a1;
    xa[(rr*2+0)*148 + 128 + col] = a0;
    xa[(rr*2+1)*148 + 128 + col] = a1;
  }
  __syncthreads();
  glayer128<144, 148, 132, true>(xa, gW1, gb1, gg1v, gbt1, xb, tid);   // gating h -> xb
  __syncthreads();
  glayer64<128, 132, 148>(xb, gW2, gb2, xa, tid);                      // -> xa[0..63]
  __syncthreads();
  { // g3: xa[32,64] @ gW3[64,8] -> logits; softmax -> gates
    int col = tid & 7, rr = tid >> 3;            // rr 0..31
    float a = gb3[col];
    for (int k = 0; k < 64; k++) a += xa[rr*148 + k] * gW3[k*8 + col];
    out_logits[(size_t)(row0 + rr)*8 + col] = a;
    float m = a;
    m = fmaxf(m, __shfl_xor(m, 1, 64));
    m = fmaxf(m, __shfl_xor(m, 2, 64));
    m = fmaxf(m, __shfl_xor(m, 4, 64));
    float ex = __expf(a - m);
    float s = ex;
    s += __shfl_xor(s, 1, 64); s += __shfl_xor(s, 2, 64); s += __shfl_xor(s, 4, 64);
    out_gates[(size_t)(row0 + rr)*8 + col] = ex / s;
  }
}

// ---------------- final mix: mixed[b] = sum_e eo[b,e]*gates[b,e] ----------------
__global__ __launch_bounds__(256) void mix_kernel(const float* __restrict__ eo, const float* __restrict__ gates,
                                                  float* __restrict__ mixed){
  int t = blockIdx.x * 256 + threadIdx.x;
  if (t < 32768){
    const float4* a = (const float4*)(eo + (size_t)t*8);
    const float4* gg = (const float4*)(gates + (size_t)t*8);
    float4 a0 = a[0], a1 = a[1], g0 = gg[0], g1 = gg[1];
    mixed[t] = a0.x*g0.x + a0.y*g0.y + a0.z*g0.z + a0.w*g0.w
             + a1.x*g1.x + a1.y*g1.y + a1.z*g1.z + a1.w*g1.w;
  }
}

extern "C" void kernel_launch(void* const* d_in, const int* in_sizes, int n_in,
                              void* d_out, int out_size, void* d_ws, size_t ws_size,
                              hipStream_t stream)
{
  if (n_in < 36 || in_sizes[0] != 32768*128 || out_size < 1081344) return;

  const float* expert_features = (const float*)d_in[0];
  const float* gate_features   = (const float*)d_in[1];
  const float* eW1 = (const float*)d_in[2];
  const float* eb1 = (const float*)d_in[3];
  const float* eg1 = (const float*)d_in[4];
  const float* ebt1= (const float*)d_in[5];
  const float* eW2 = (const float*)d_in[6];
  const float* eb2 = (const float*)d_in[7];
  const float* eg2 = (const float*)d_in[8];
  const float* ebt2= (const float*)d_in[9];
  const float* eW3 = (const float*)d_in[10];
  const float* eb3 = (const float*)d_in[11];
  const float* eg3 = (const float*)d_in[12];
  const float* ebt3= (const float*)d_in[13];
  const float* eW4 = (const float*)d_in[14];
  const float* eb4 = (const float*)d_in[15];
  const float* bW1 = (const float*)d_in[16];
  const float* bb1 = (const float*)d_in[17];
  const float* bg1 = (const float*)d_in[18];
  const float* bbt1= (const float*)d_in[19];
  const float* bW2 = (const float*)d_in[20];
  const float* bb2 = (const float*)d_in[21];
  const float* bg2 = (const float*)d_in[22];
  const float* bbt2= (const float*)d_in[23];
  const float* encW1 = (const float*)d_in[24];
  const float* encb1 = (const float*)d_in[25];
  const float* encW2 = (const float*)d_in[26];
  const float* encb2 = (const float*)d_in[27];
  const float* gW1 = (const float*)d_in[28];
  const float* gb1 = (const float*)d_in[29];
  const float* gg1 = (const float*)d_in[30];
  const float* gbt1= (const float*)d_in[31];
  const float* gW2 = (const float*)d_in[32];
  const float* gb2 = (const float*)d_in[33];
  const float* gW3 = (const float*)d_in[34];
  const float* gb3 = (const float*)d_in[35];

  float* out        = (float*)d_out;
  float* out_mixed  = out;                 // [B]
  float* out_z      = out + 32768;         // [B,16]
  float* out_logits = out + 557056;        // [B,8]
  float* out_gates  = out + 819200;        // [B,8]

  char* ws = (char*)d_ws;
  size_t off = 0;
  auto walloc = [&](size_t bytes) -> char* { char* p = ws + off; off += (bytes + 255) & ~(size_t)255; return p; };
  unsigned short* Xp  = (unsigned short*)walloc((size_t)4194304 * 2);  // packed X, bf16
  unsigned short* W1p = (unsigned short*)walloc((size_t)524288  * 2);
  unsigned short* W2p = (unsigned short*)walloc((size_t)1048576 * 2);
  unsigned short* W3p = (unsigned short*)walloc((size_t)262144  * 2);
  float*          w4p = (float*)walloc((size_t)1024 * 4);
  float*          eo  = (float*)walloc((size_t)262144 * 4);            // expert outputs [B,8]
  if (off > ws_size) return;  // workspace too small -> clean failure signal

  // --- pack ---
  pack_x_kernel<<<2048, 256, 0, stream>>>(expert_features, Xp);
  pack_w_kernel<<< 900, 256, 0, stream>>>(eW1, eW2, eW3, eW4, W1p, W2p, W3p, w4p);

  // --- gate path (fused, fp32) ---
  gate_fused<<<1024, 256, 0, stream>>>(gate_features,
                                       bW1, bb1, bg1, bbt1, bW2, bb2, bg2, bbt2,
                                       encW1, encb1, encW2, encb2,
                                       gW1, gb1, gg1, gbt1, gW2, gb2, gW3, gb3,
                                       out_z, out_logits, out_gates);

  // --- fused experts (bf16 MFMA) ---
  expert_kernel<<<dim3(1024, 8), 256, 0, stream>>>(Xp, W1p, W2p, W3p, w4p,
                                                   eb1, eg1, ebt1, eb2, eg2, ebt2, eb3, eg3, ebt3,
                                                   eb4, eo);

  // --- mix ---
  mix_kernel<<<128, 256, 0, stream>>>(eo, out_gates, out_mixed);
}

// Round 6
// 435.361 us; speedup vs baseline: 1.4858x; 1.0879x over previous
//
#include <hip/hip_runtime.h>
#include <hip/hip_bf16.h>

// LatentSensorMoE: fused bf16-MFMA expert MLPs + fp32 gate path, single main dispatch.
// B=32768, EIN=128, E=8, experts 128->512->256->128->1 (LN+SiLU per hidden),
// gate: 64->128(LN,SiLU)->128(LN,SiLU); enc 128->64(SiLU)->16; gating 144->128(LN,SiLU)->64(SiLU)->8->softmax.
// Outputs (fp32, concat): mixed[B] | z[B,16] | logits[B,8] | gates[B,8]
//
// R6 = R5 (passing, 473us) + (a) silu via v_rcp_f32 (R3/R4 evidence: numerics benign),
// (b) gate fused into the expert dispatch as blockIdx.y==8 (grid 1024x9), LDS unioned
// in one 35840B carve-out. Quarantined (R3/R4 bug set): bias-post-loop epilogue,
// nm-form LN, 16-row gate rewrite — NOT used.

typedef __attribute__((ext_vector_type(8))) short bf16x8;   // 8 bf16 = 4 VGPR (MFMA frag)
typedef __attribute__((ext_vector_type(4))) float f32x4;

#define DEV static __device__ __forceinline__

DEV float b2f(unsigned short u){ union { unsigned int i; float f; } x; x.i = ((unsigned int)u) << 16; return x.f; }
DEV unsigned short f2b(float f){
  union { float f; unsigned int i; } x; x.f = f;
  return (unsigned short)((x.i + 0x7fffu + ((x.i >> 16) & 1u)) >> 16);  // RNE
}
DEV unsigned int pk2(float a, float b){
  __hip_bfloat162 h = __float22bfloat162_rn(make_float2(a, b));        // v_cvt_pk_bf16_f32
  union { __hip_bfloat162 h; unsigned int u; } u; u.h = h; return u.u;
}
// silu via fast rcp (v_rcp_f32, ~5 VALU) instead of IEEE div sequence (~10 VALU)
DEV float silu_f(float v){ return v * __builtin_amdgcn_rcpf(1.0f + __expf(-v)); }

// ---------------- pack kernels: fp32 -> bf16 MFMA fragment layouts ----------------
// A-frag (16x16x32): lane l holds A[m=l&15][k=(l>>4)*8+j], j=0..7  -> 16B/lane contiguous
// B-frag:            lane l holds B[k=(l>>4)*8+j][n=l&15]
// Stage s output is written to LDS in permuted k' order; W(s+1) k-dim pre-permuted to match:
//  pi1: col c=(w*128+nt*16+c0) -> k' = w*128 + c0*8 + nt   (nt<8)
//  pi2: col c=(w*64 +nt*16+c0) -> k' = w*64  + c0*4 + nt   (nt<4)
//  pi3: col c=(w*32 +nt*16+c0) -> k' = w*32  + c0*2 + nt   (nt<2)

__global__ __launch_bounds__(256) void pack_x_kernel(const float* __restrict__ X, unsigned short* __restrict__ Xp){
  int t = blockIdx.x * 256 + threadIdx.x;          // [0, 2048*4*64)
  int l = t & 63, kb = (t >> 6) & 3, mtg = t >> 8; // mtg: 16-row tile id [0,2048)
  int row = mtg * 16 + (l & 15);
  int k0  = kb * 32 + (l >> 4) * 8;
  const float* src = X + (size_t)row * 128 + k0;
  bf16x8 o;
  #pragma unroll
  for (int j = 0; j < 8; j++) o[j] = (short)f2b(src[j]);
  *(bf16x8*)(Xp + (size_t)t * 8) = o;
}

// combined weight pack: blocks [0,256)=W1, [256,768)=W2, [768,896)=W3, [896,900)=w4
__global__ __launch_bounds__(256) void pack_w_kernel(const float* __restrict__ eW1, const float* __restrict__ eW2,
                                                     const float* __restrict__ eW3, const float* __restrict__ eW4,
                                                     unsigned short* __restrict__ W1p, unsigned short* __restrict__ W2p,
                                                     unsigned short* __restrict__ W3p, float* __restrict__ w4p){
  int b = blockIdx.x;
  if (b < 256){
    int t = b * 256 + threadIdx.x;                 // [0, 65536)
    int l = t & 63, kb = (t >> 6) & 3, ntg = (t >> 8) & 31, e = t >> 13;
    int q = l >> 4, c0 = l & 15, n = ntg * 16 + c0;
    bf16x8 o;
    #pragma unroll
    for (int j = 0; j < 8; j++){ int k = kb*32 + q*8 + j; o[j] = (short)f2b(eW1[((size_t)e*128 + k)*512 + n]); }
    *(bf16x8*)(W1p + (size_t)t * 8) = o;
  } else if (b < 768){
    int t = (b - 256) * 256 + threadIdx.x;         // [0, 131072)
    int l = t & 63, kb = (t >> 6) & 15, ntg = (t >> 10) & 15, e = t >> 14;
    int q = l >> 4, c0 = l & 15, n = ntg * 16 + c0;
    bf16x8 o;
    #pragma unroll
    for (int j = 0; j < 8; j++){
      int kp = kb*32 + q*8 + j;                                        // k' in pi1 space
      int c = (kp >> 7) * 128 + (kp & 7) * 16 + ((kp >> 3) & 15);      // pi1^-1
      o[j] = (short)f2b(eW2[((size_t)e*512 + c)*256 + n]);
    }
    *(bf16x8*)(W2p + (size_t)t * 8) = o;
  } else if (b < 896){
    int t = (b - 768) * 256 + threadIdx.x;         // [0, 32768)
    int l = t & 63, kb = (t >> 6) & 7, ntg = (t >> 9) & 7, e = t >> 12;
    int q = l >> 4, c0 = l & 15, n = ntg * 16 + c0;
    bf16x8 o;
    #pragma unroll
    for (int j = 0; j < 8; j++){
      int kp = kb*32 + q*8 + j;                                        // k' in pi2 space
      int c = (kp >> 6) * 64 + (kp & 3) * 16 + ((kp >> 2) & 15);       // pi2^-1
      o[j] = (short)f2b(eW3[((size_t)e*256 + c)*128 + n]);
    }
    *(bf16x8*)(W3p + (size_t)t * 8) = o;
  } else {
    int t = (b - 896) * 256 + threadIdx.x;
    if (t < 1024){
      int e = t >> 7, kp = t & 127;
      int c = (kp >> 5) * 32 + (kp & 1) * 16 + ((kp >> 1) & 15);       // pi3^-1
      w4p[t] = eW4[e * 128 + c];
    }
  }
}

// ---------------- gate layers (round-2-verified structure, 32 rows/block) ----------------
// N=128 layer: thread tile 4 rows x 4 cols
template<int K, int PIN, int POUT, bool LN>
DEV void glayer128(const float* __restrict__ xs, const float* __restrict__ W, const float* __restrict__ b,
                   const float* __restrict__ g, const float* __restrict__ btv, float* __restrict__ ys, int tid)
{
  const int cg = tid & 31, rg = tid >> 5;
  const int col0 = cg * 4, row0 = rg * 4;
  float4 bv = *(const float4*)(b + col0);
  float acc[4][4];
  #pragma unroll
  for (int r = 0; r < 4; r++){ acc[r][0] = bv.x; acc[r][1] = bv.y; acc[r][2] = bv.z; acc[r][3] = bv.w; }
  for (int k = 0; k < K; k += 4){
    float4 x0 = *(const float4*)(xs + (row0+0)*PIN + k);
    float4 x1 = *(const float4*)(xs + (row0+1)*PIN + k);
    float4 x2 = *(const float4*)(xs + (row0+2)*PIN + k);
    float4 x3 = *(const float4*)(xs + (row0+3)*PIN + k);
    float4 w0 = *(const float4*)(W + (size_t)(k+0)*128 + col0);
    float4 w1 = *(const float4*)(W + (size_t)(k+1)*128 + col0);
    float4 w2 = *(const float4*)(W + (size_t)(k+2)*128 + col0);
    float4 w3 = *(const float4*)(W + (size_t)(k+3)*128 + col0);
    const float xr[4][4] = {{x0.x,x0.y,x0.z,x0.w},{x1.x,x1.y,x1.z,x1.w},{x2.x,x2.y,x2.z,x2.w},{x3.x,x3.y,x3.z,x3.w}};
    const float wr[4][4] = {{w0.x,w0.y,w0.z,w0.w},{w1.x,w1.y,w1.z,w1.w},{w2.x,w2.y,w2.z,w2.w},{w3.x,w3.y,w3.z,w3.w}};
    #pragma unroll
    for (int kk = 0; kk < 4; kk++)
      #pragma unroll
      for (int r = 0; r < 4; r++)
        #pragma unroll
        for (int c = 0; c < 4; c++) acc[r][c] += xr[r][kk] * wr[kk][c];
  }
  float mu[4], rs[4];
  if (LN){
    #pragma unroll
    for (int r = 0; r < 4; r++){
      float s = acc[r][0] + acc[r][1] + acc[r][2] + acc[r][3];
      float qq = acc[r][0]*acc[r][0] + acc[r][1]*acc[r][1] + acc[r][2]*acc[r][2] + acc[r][3]*acc[r][3];
      #pragma unroll
      for (int off = 1; off < 32; off <<= 1){ s += __shfl_xor(s, off, 64); qq += __shfl_xor(qq, off, 64); }
      float m = s * (1.0f/128.0f);
      mu[r] = m; rs[r] = rsqrtf(qq * (1.0f/128.0f) - m*m + 1e-5f);
    }
    float4 gv = *(const float4*)(g + col0);
    float4 tv = *(const float4*)(btv + col0);
    const float gr[4] = {gv.x, gv.y, gv.z, gv.w};
    const float tr[4] = {tv.x, tv.y, tv.z, tv.w};
    #pragma unroll
    for (int r = 0; r < 4; r++)
      #pragma unroll
      for (int c = 0; c < 4; c++) acc[r][c] = (acc[r][c] - mu[r]) * rs[r] * gr[c] + tr[c];
  }
  #pragma unroll
  for (int r = 0; r < 4; r++){
    float4 o;
    o.x = silu_f(acc[r][0]); o.y = silu_f(acc[r][1]); o.z = silu_f(acc[r][2]); o.w = silu_f(acc[r][3]);
    *(float4*)(ys + (row0+r)*POUT + col0) = o;
  }
}

// N=64, SiLU only: thread tile 2 rows x 4 cols
template<int K, int PIN, int POUT>
DEV void glayer64(const float* __restrict__ xs, const float* __restrict__ W, const float* __restrict__ b,
                  float* __restrict__ ys, int tid)
{
  const int cg = tid & 15, rg = tid >> 4;
  const int col0 = cg * 4, row0 = rg * 2;
  float4 bv = *(const float4*)(b + col0);
  float acc[2][4];
  #pragma unroll
  for (int r = 0; r < 2; r++){ acc[r][0] = bv.x; acc[r][1] = bv.y; acc[r][2] = bv.z; acc[r][3] = bv.w; }
  for (int k = 0; k < K; k += 4){
    float4 x0 = *(const float4*)(xs + (row0+0)*PIN + k);
    float4 x1 = *(const float4*)(xs + (row0+1)*PIN + k);
    float4 w0 = *(const float4*)(W + (size_t)(k+0)*64 + col0);
    float4 w1 = *(const float4*)(W + (size_t)(k+1)*64 + col0);
    float4 w2 = *(const float4*)(W + (size_t)(k+2)*64 + col0);
    float4 w3 = *(const float4*)(W + (size_t)(k+3)*64 + col0);
    const float xr[2][4] = {{x0.x,x0.y,x0.z,x0.w},{x1.x,x1.y,x1.z,x1.w}};
    const float wr[4][4] = {{w0.x,w0.y,w0.z,w0.w},{w1.x,w1.y,w1.z,w1.w},{w2.x,w2.y,w2.z,w2.w},{w3.x,w3.y,w3.z,w3.w}};
    #pragma unroll
    for (int kk = 0; kk < 4; kk++)
      #pragma unroll
      for (int r = 0; r < 2; r++)
        #pragma unroll
        for (int c = 0; c < 4; c++) acc[r][c] += xr[r][kk] * wr[kk][c];
  }
  #pragma unroll
  for (int r = 0; r < 2; r++){
    float4 o;
    o.x = silu_f(acc[r][0]); o.y = silu_f(acc[r][1]); o.z = silu_f(acc[r][2]); o.w = silu_f(acc[r][3]);
    *(float4*)(ys + (row0+r)*POUT + col0) = o;
  }
}

DEV void gate_body(unsigned char* smem, int bx, int tid,
                   const float* __restrict__ gf,
                   const float* __restrict__ bW1, const float* __restrict__ bb1, const float* __restrict__ bg1, const float* __restrict__ bbt1,
                   const float* __restrict__ bW2, const float* __restrict__ bb2, const float* __restrict__ bg2, const float* __restrict__ bbt2,
                   const float* __restrict__ encW1, const float* __restrict__ encb1, const float* __restrict__ encW2, const float* __restrict__ encb2,
                   const float* __restrict__ gW1, const float* __restrict__ gb1, const float* __restrict__ gg1v, const float* __restrict__ gbt1,
                   const float* __restrict__ gW2, const float* __restrict__ gb2, const float* __restrict__ gW3, const float* __restrict__ gb3,
                   float* __restrict__ out_z, float* __restrict__ out_logits, float* __restrict__ out_gates)
{
  const int row0 = bx * 32;
  float* xa = (float*)smem;                  // [0, 18944) B : 32*148 floats
  float* xb = (float*)(smem + 18944);        // [18944, 35840) B : 32*132 floats

  // load gate_features [32,64]
  for (int idx = tid; idx < 32*64; idx += 256){
    int r = idx >> 6, k = idx & 63;
    xa[r*148 + k] = gf[(size_t)(row0 + r)*64 + k];
  }
  __syncthreads();
  glayer128<64, 148, 132, true>(xa, bW1, bb1, bg1, bbt1, xb, tid);     // h1 -> xb
  __syncthreads();
  glayer128<128, 132, 148, true>(xb, bW2, bb2, bg2, bbt2, xa, tid);    // h2 -> xa[0..127]
  __syncthreads();
  glayer64<128, 148, 132>(xa, encW1, encb1, xb, tid);                  // enc1 -> xb[0..63]
  __syncthreads();
  { // enc2: xb[32,64] @ encW2[64,16] -> z; write out_z and xa cols 128..143
    int col = tid & 15, rr = tid >> 4;           // rr 0..15 -> rows rr*2, rr*2+1
    float a0 = encb2[col], a1 = a0;
    for (int k = 0; k < 64; k++){
      float wv = encW2[k*16 + col];
      a0 += xb[(rr*2+0)*132 + k] * wv;
      a1 += xb[(rr*2+1)*132 + k] * wv;
    }
    out_z[(size_t)(row0 + rr*2+0)*16 + col] = a0;
    out_z[(size_t)(row0 + rr*2+1)*16 + col] = a1;
    xa[(rr*2+0)*148 + 128 + col] = a0;
    xa[(rr*2+1)*148 + 128 + col] = a1;
  }
  __syncthreads();
  glayer128<144, 148, 132, true>(xa, gW1, gb1, gg1v, gbt1, xb, tid);   // gating h -> xb
  __syncthreads();
  glayer64<128, 132, 148>(xb, gW2, gb2, xa, tid);                      // -> xa[0..63]
  __syncthreads();
  { // g3: xa[32,64] @ gW3[64,8] -> logits; softmax -> gates
    int col = tid & 7, rr = tid >> 3;            // rr 0..31
    float a = gb3[col];
    for (int k = 0; k < 64; k++) a += xa[rr*148 + k] * gW3[k*8 + col];
    out_logits[(size_t)(row0 + rr)*8 + col] = a;
    float m = a;
    m = fmaxf(m, __shfl_xor(m, 1, 64));
    m = fmaxf(m, __shfl_xor(m, 2, 64));
    m = fmaxf(m, __shfl_xor(m, 4, 64));
    float ex = __expf(a - m);
    float s = ex;
    s += __shfl_xor(s, 1, 64); s += __shfl_xor(s, 2, 64); s += __shfl_xor(s, 4, 64);
    out_gates[(size_t)(row0 + rr)*8 + col] = ex / s;
  }
}

// ---------------- main fused dispatch: grid (1024, 9) ----------------
// blockIdx.y < 8 : expert body (32 rows x expert y). blockIdx.y == 8 : gate body.
// LDS: one 35840B carve-out unioned across both bodies -> 4 blocks/CU at (256,4).
#define MFMA_BF16 __builtin_amdgcn_mfma_f32_16x16x32_bf16

__global__ __launch_bounds__(256, 4)
void fused_main(const unsigned short* __restrict__ Xp,
                const unsigned short* __restrict__ W1p,
                const unsigned short* __restrict__ W2p,
                const unsigned short* __restrict__ W3p,
                const float* __restrict__ w4p,
                const float* __restrict__ eb1, const float* __restrict__ eg1, const float* __restrict__ ebt1,
                const float* __restrict__ eb2, const float* __restrict__ eg2, const float* __restrict__ ebt2,
                const float* __restrict__ eb3, const float* __restrict__ eg3, const float* __restrict__ ebt3,
                const float* __restrict__ eb4, float* __restrict__ eo,
                const float* __restrict__ gf,
                const float* __restrict__ bW1, const float* __restrict__ bb1, const float* __restrict__ bg1, const float* __restrict__ bbt1,
                const float* __restrict__ bW2, const float* __restrict__ bb2, const float* __restrict__ bg2, const float* __restrict__ bbt2,
                const float* __restrict__ encW1, const float* __restrict__ encb1, const float* __restrict__ encW2, const float* __restrict__ encb2,
                const float* __restrict__ gW1, const float* __restrict__ gb1, const float* __restrict__ gg1v, const float* __restrict__ gbt1,
                const float* __restrict__ gW2, const float* __restrict__ gb2, const float* __restrict__ gW3, const float* __restrict__ gb3,
                float* __restrict__ out_z, float* __restrict__ out_logits, float* __restrict__ out_gates)
{
  __shared__ __align__(16) unsigned char smem[35840];
  const int tid = threadIdx.x;

  if (blockIdx.y == 8){
    gate_body(smem, blockIdx.x, tid, gf,
              bW1, bb1, bg1, bbt1, bW2, bb2, bg2, bbt2,
              encW1, encb1, encW2, encb2,
              gW1, gb1, gg1v, gbt1, gW2, gb2, gW3, gb3,
              out_z, out_logits, out_gates);
    return;
  }

  const int e = blockIdx.y, bt = blockIdx.x;
  const int w = tid >> 6, l = tid & 63;
  const int q = l >> 4, c0 = l & 15;

  unsigned short* h1 = (unsigned short*)smem;          // [0, 33280) B
  float* redS = (float*)(smem + 33280);                // 128 floats
  float* redQ = (float*)(smem + 33792);                // 128 floats
  float* muS  = (float*)(smem + 34304);                // 32 floats
  float* rsS  = (float*)(smem + 34432);                // 32 floats
  unsigned short* h2 = h1;                 // [0, 16896) B — h1 dead after stage-2 k-loop barrier
  unsigned short* h3 = h1 + 32 * 264;      // [16896, 25600) B — disjoint from h2

  // ===== stage 1: X[32,128] @ W1[128,512], +b (as C-init), LN, SiLU -> h1 (k' = pi1) =====
  {
    float bv[8], gv[8], tv[8];
    #pragma unroll
    for (int nt = 0; nt < 8; nt++){
      int col = w*128 + nt*16 + c0;
      bv[nt] = eb1[e*512 + col]; gv[nt] = eg1[e*512 + col]; tv[nt] = ebt1[e*512 + col];
    }
    f32x4 acc[2][8];
    #pragma unroll
    for (int m = 0; m < 2; m++)
      #pragma unroll
      for (int nt = 0; nt < 8; nt++) acc[m][nt] = (f32x4){bv[nt],bv[nt],bv[nt],bv[nt]};
    #pragma unroll
    for (int kb = 0; kb < 4; kb++){
      bf16x8 a0 = *(const bf16x8*)(Xp + ((size_t)((bt*2 + 0)*4 + kb)*64 + l)*8);
      bf16x8 a1 = *(const bf16x8*)(Xp + ((size_t)((bt*2 + 1)*4 + kb)*64 + l)*8);
      #pragma unroll
      for (int nt = 0; nt < 8; nt++){
        int ntg = w*8 + nt;
        bf16x8 b = *(const bf16x8*)(W1p + ((size_t)((e*32 + ntg)*4 + kb)*64 + l)*8);
        acc[0][nt] = MFMA_BF16(a0, b, acc[0][nt], 0, 0, 0);
        acc[1][nt] = MFMA_BF16(a1, b, acc[1][nt], 0, 0, 0);
      }
    }
    float s[2][4] = {}, sq[2][4] = {};
    #pragma unroll
    for (int nt = 0; nt < 8; nt++)
      #pragma unroll
      for (int m = 0; m < 2; m++)
        #pragma unroll
        for (int r = 0; r < 4; r++){
          float v = acc[m][nt][r];
          s[m][r] += v; sq[m][r] += v*v;
        }
    #pragma unroll
    for (int m = 0; m < 2; m++)
      #pragma unroll
      for (int r = 0; r < 4; r++){
        float a = s[m][r], b = sq[m][r];
        #pragma unroll
        for (int off = 1; off < 16; off <<= 1){ a += __shfl_xor(a, off, 64); b += __shfl_xor(b, off, 64); }
        if (c0 == 0){ int row = m*16 + q*4 + r; redS[row*4 + w] = a; redQ[row*4 + w] = b; }
      }
    __syncthreads();
    if (tid < 32){
      float S = 0.f, Q = 0.f;
      #pragma unroll
      for (int i = 0; i < 4; i++){ S += redS[tid*4 + i]; Q += redQ[tid*4 + i]; }
      float mu = S * (1.0f/512.0f);
      float var = Q * (1.0f/512.0f) - mu*mu;
      muS[tid] = mu; rsS[tid] = rsqrtf(var + 1e-5f);
    }
    __syncthreads();
    #pragma unroll
    for (int m = 0; m < 2; m++)
      #pragma unroll
      for (int r = 0; r < 4; r++){
        int row = m*16 + q*4 + r;
        float mu = muS[row], rs = rsS[row];
        float v[8];
        #pragma unroll
        for (int nt = 0; nt < 8; nt++) v[nt] = silu_f((acc[m][nt][r] - mu) * rs * gv[nt] + tv[nt]);
        uint4 pk;
        pk.x = pk2(v[0], v[1]); pk.y = pk2(v[2], v[3]); pk.z = pk2(v[4], v[5]); pk.w = pk2(v[6], v[7]);
        *(uint4*)(h1 + row*520 + w*128 + c0*8) = pk;   // ds_write_b128, k' = w*128+c0*8+nt
      }
  }
  __syncthreads();

  // ===== stage 2: h1[32,512(pi1)] @ W2p, +b, LN, SiLU -> h2 (k' = pi2, aliases h1) =====
  {
    float bv[4], gv[4], tv[4];
    #pragma unroll
    for (int nt = 0; nt < 4; nt++){
      int col = w*64 + nt*16 + c0;
      bv[nt] = eb2[e*256 + col]; gv[nt] = eg2[e*256 + col]; tv[nt] = ebt2[e*256 + col];
    }
    f32x4 acc[2][4];
    #pragma unroll
    for (int m = 0; m < 2; m++)
      #pragma unroll
      for (int nt = 0; nt < 4; nt++) acc[m][nt] = (f32x4){bv[nt],bv[nt],bv[nt],bv[nt]};
    #pragma unroll 2
    for (int kb = 0; kb < 16; kb++){
      bf16x8 a0 = *(const bf16x8*)(h1 + (0  + c0)*520 + kb*32 + q*8);
      bf16x8 a1 = *(const bf16x8*)(h1 + (16 + c0)*520 + kb*32 + q*8);
      #pragma unroll
      for (int nt = 0; nt < 4; nt++){
        int ntg = w*4 + nt;
        bf16x8 b = *(const bf16x8*)(W2p + ((size_t)((e*16 + ntg)*16 + kb)*64 + l)*8);
        acc[0][nt] = MFMA_BF16(a0, b, acc[0][nt], 0, 0, 0);
        acc[1][nt] = MFMA_BF16(a1, b, acc[1][nt], 0, 0, 0);
      }
    }
    float s[2][4] = {}, sq[2][4] = {};
    #pragma unroll
    for (int nt = 0; nt < 4; nt++)
      #pragma unroll
      for (int m = 0; m < 2; m++)
        #pragma unroll
        for (int r = 0; r < 4; r++){
          float v = acc[m][nt][r];
          s[m][r] += v; sq[m][r] += v*v;
        }
    #pragma unroll
    for (int m = 0; m < 2; m++)
      #pragma unroll
      for (int r = 0; r < 4; r++){
        float a = s[m][r], b = sq[m][r];
        #pragma unroll
        for (int off = 1; off < 16; off <<= 1){ a += __shfl_xor(a, off, 64); b += __shfl_xor(b, off, 64); }
        if (c0 == 0){ int row = m*16 + q*4 + r; redS[row*4 + w] = a; redQ[row*4 + w] = b; }
      }
    __syncthreads();   // all stage-2 k-loop reads of h1 complete here -> h2 may overwrite h1
    if (tid < 32){
      float S = 0.f, Q = 0.f;
      #pragma unroll
      for (int i = 0; i < 4; i++){ S += redS[tid*4 + i]; Q += redQ[tid*4 + i]; }
      float mu = S * (1.0f/256.0f);
      float var = Q * (1.0f/256.0f) - mu*mu;
      muS[tid] = mu; rsS[tid] = rsqrtf(var + 1e-5f);
    }
    __syncthreads();
    #pragma unroll
    for (int m = 0; m < 2; m++)
      #pragma unroll
      for (int r = 0; r < 4; r++){
        int row = m*16 + q*4 + r;
        float mu = muS[row], rs = rsS[row];
        float v[4];
        #pragma unroll
        for (int nt = 0; nt < 4; nt++) v[nt] = silu_f((acc[m][nt][r] - mu) * rs * gv[nt] + tv[nt]);
        uint2 pk; pk.x = pk2(v[0], v[1]); pk.y = pk2(v[2], v[3]);
        *(uint2*)(h2 + row*264 + w*64 + c0*4) = pk;    // ds_write_b64, k' = w*64+c0*4+nt
      }
  }
  __syncthreads();

  // ===== stage 3: h2[32,256(pi2)] @ W3p, +b, LN, SiLU -> h3 (k' = pi3) =====
  {
    float bv[2], gv[2], tv[2];
    #pragma unroll
    for (int nt = 0; nt < 2; nt++){
      int col = w*32 + nt*16 + c0;
      bv[nt] = eb3[e*128 + col]; gv[nt] = eg3[e*128 + col]; tv[nt] = ebt3[e*128 + col];
    }
    f32x4 acc[2][2];
    #pragma unroll
    for (int m = 0; m < 2; m++)
      #pragma unroll
      for (int nt = 0; nt < 2; nt++) acc[m][nt] = (f32x4){bv[nt],bv[nt],bv[nt],bv[nt]};
    #pragma unroll 2
    for (int kb = 0; kb < 8; kb++){
      bf16x8 a0 = *(const bf16x8*)(h2 + (0  + c0)*264 + kb*32 + q*8);
      bf16x8 a1 = *(const bf16x8*)(h2 + (16 + c0)*264 + kb*32 + q*8);
      #pragma unroll
      for (int nt = 0; nt < 2; nt++){
        int ntg = w*2 + nt;
        bf16x8 b = *(const bf16x8*)(W3p + ((size_t)((e*8 + ntg)*8 + kb)*64 + l)*8);
        acc[0][nt] = MFMA_BF16(a0, b, acc[0][nt], 0, 0, 0);
        acc[1][nt] = MFMA_BF16(a1, b, acc[1][nt], 0, 0, 0);
      }
    }
    float s[2][4] = {}, sq[2][4] = {};
    #pragma unroll
    for (int nt = 0; nt < 2; nt++)
      #pragma unroll
      for (int m = 0; m < 2; m++)
        #pragma unroll
        for (int r = 0; r < 4; r++){
          float v = acc[m][nt][r];
          s[m][r] += v; sq[m][r] += v*v;
        }
    #pragma unroll
    for (int m = 0; m < 2; m++)
      #pragma unroll
      for (int r = 0; r < 4; r++){
        float a = s[m][r], b = sq[m][r];
        #pragma unroll
        for (int off = 1; off < 16; off <<= 1){ a += __shfl_xor(a, off, 64); b += __shfl_xor(b, off, 64); }
        if (c0 == 0){ int row = m*16 + q*4 + r; redS[row*4 + w] = a; redQ[row*4 + w] = b; }
      }
    __syncthreads();   // all stage-3 k-loop reads of h2 complete here
    if (tid < 32){
      float S = 0.f, Q = 0.f;
      #pragma unroll
      for (int i = 0; i < 4; i++){ S += redS[tid*4 + i]; Q += redQ[tid*4 + i]; }
      float mu = S * (1.0f/128.0f);
      float var = Q * (1.0f/128.0f) - mu*mu;
      muS[tid] = mu; rsS[tid] = rsqrtf(var + 1e-5f);
    }
    __syncthreads();
    #pragma unroll
    for (int m = 0; m < 2; m++)
      #pragma unroll
      for (int r = 0; r < 4; r++){
        int row = m*16 + q*4 + r;
        float mu = muS[row], rs = rsS[row];
        float v0 = silu_f((acc[m][0][r] - mu) * rs * gv[0] + tv[0]);
        float v1 = silu_f((acc[m][1][r] - mu) * rs * gv[1] + tv[1]);
        *(unsigned int*)(h3 + row*136 + w*32 + c0*2) = pk2(v0, v1);  // ds_write_b32, k' = w*32+c0*2+nt
      }
  }
  __syncthreads();

  // ===== stage 4: h3[32,128(pi3)] . w4p[e] + eb4 -> eo[b, e] =====
  {
    int row = tid >> 3, sub = tid & 7;
    bf16x8 v0 = *(const bf16x8*)(h3 + row*136 + sub*16);
    bf16x8 v1 = *(const bf16x8*)(h3 + row*136 + sub*16 + 8);
    float a = 0.f;
    #pragma unroll
    for (int j = 0; j < 8; j++) a += b2f((unsigned short)v0[j]) * w4p[e*128 + sub*16 + j];
    #pragma unroll
    for (int j = 0; j < 8; j++) a += b2f((unsigned short)v1[j]) * w4p[e*128 + sub*16 + 8 + j];
    a += __shfl_xor(a, 1, 64); a += __shfl_xor(a, 2, 64); a += __shfl_xor(a, 4, 64);
    if (sub == 0) eo[(size_t)(bt*32 + row)*8 + e] = a + eb4[e];
  }
}

// ---------------- final mix: mixed[b] = sum_e eo[b,e]*gates[b,e] ----------------
__global__ __launch_bounds__(256) void mix_kernel(const float* __restrict__ eo, const float* __restrict__ gates,
                                                  float* __restrict__ mixed){
  int t = blockIdx.x * 256 + threadIdx.x;
  if (t < 32768){
    const float4* a = (const float4*)(eo + (size_t)t*8);
    const float4* gg = (const float4*)(gates + (size_t)t*8);
    float4 a0 = a[0], a1 = a[1], g0 = gg[0], g1 = gg[1];
    mixed[t] = a0.x*g0.x + a0.y*g0.y + a0.z*g0.z + a0.w*g0.w
             + a1.x*g1.x + a1.y*g1.y + a1.z*g1.z + a1.w*g1.w;
  }
}

extern "C" void kernel_launch(void* const* d_in, const int* in_sizes, int n_in,
                              void* d_out, int out_size, void* d_ws, size_t ws_size,
                              hipStream_t stream)
{
  if (n_in < 36 || in_sizes[0] != 32768*128 || out_size < 1081344) return;

  const float* expert_features = (const float*)d_in[0];
  const float* gate_features   = (const float*)d_in[1];
  const float* eW1 = (const float*)d_in[2];
  const float* eb1 = (const float*)d_in[3];
  const float* eg1 = (const float*)d_in[4];
  const float* ebt1= (const float*)d_in[5];
  const float* eW2 = (const float*)d_in[6];
  const float* eb2 = (const float*)d_in[7];
  const float* eg2 = (const float*)d_in[8];
  const float* ebt2= (const float*)d_in[9];
  const float* eW3 = (const float*)d_in[10];
  const float* eb3 = (const float*)d_in[11];
  const float* eg3 = (const float*)d_in[12];
  const float* ebt3= (const float*)d_in[13];
  const float* eW4 = (const float*)d_in[14];
  const float* eb4 = (const float*)d_in[15];
  const float* bW1 = (const float*)d_in[16];
  const float* bb1 = (const float*)d_in[17];
  const float* bg1 = (const float*)d_in[18];
  const float* bbt1= (const float*)d_in[19];
  const float* bW2 = (const float*)d_in[20];
  const float* bb2 = (const float*)d_in[21];
  const float* bg2 = (const float*)d_in[22];
  const float* bbt2= (const float*)d_in[23];
  const float* encW1 = (const float*)d_in[24];
  const float* encb1 = (const float*)d_in[25];
  const float* encW2 = (const float*)d_in[26];
  const float* encb2 = (const float*)d_in[27];
  const float* gW1 = (const float*)d_in[28];
  const float* gb1 = (const float*)d_in[29];
  const float* gg1 = (const float*)d_in[30];
  const float* gbt1= (const float*)d_in[31];
  const float* gW2 = (const float*)d_in[32];
  const float* gb2 = (const float*)d_in[33];
  const float* gW3 = (const float*)d_in[34];
  const float* gb3 = (const float*)d_in[35];

  float* out        = (float*)d_out;
  float* out_mixed  = out;                 // [B]
  float* out_z      = out + 32768;         // [B,16]
  float* out_logits = out + 557056;        // [B,8]
  float* out_gates  = out + 819200;        // [B,8]

  char* ws = (char*)d_ws;
  size_t off = 0;
  auto walloc = [&](size_t bytes) -> char* { char* p = ws + off; off += (bytes + 255) & ~(size_t)255; return p; };
  unsigned short* Xp  = (unsigned short*)walloc((size_t)4194304 * 2);  // packed X, bf16
  unsigned short* W1p = (unsigned short*)walloc((size_t)524288  * 2);
  unsigned short* W2p = (unsigned short*)walloc((size_t)1048576 * 2);
  unsigned short* W3p = (unsigned short*)walloc((size_t)262144  * 2);
  float*          w4p = (float*)walloc((size_t)1024 * 4);
  float*          eo  = (float*)walloc((size_t)262144 * 4);            // expert outputs [B,8]
  if (off > ws_size) return;  // workspace too small -> clean failure signal

  // --- pack ---
  pack_x_kernel<<<2048, 256, 0, stream>>>(expert_features, Xp);
  pack_w_kernel<<< 900, 256, 0, stream>>>(eW1, eW2, eW3, eW4, W1p, W2p, W3p, w4p);

  // --- experts (y<8) + gate path (y==8) in one dispatch ---
  fused_main<<<dim3(1024, 9), 256, 0, stream>>>(Xp, W1p, W2p, W3p, w4p,
                                                eb1, eg1, ebt1, eb2, eg2, ebt2, eb3, eg3, ebt3,
                                                eb4, eo,
                                                gate_features,
                                                bW1, bb1, bg1, bbt1, bW2, bb2, bg2, bbt2,
                                                encW1, encb1, encW2, encb2,
                                                gW1, gb1, gg1, gbt1, gW2, gb2, gW3, gb3,
                                                out_z, out_logits, out_gates);

  // --- mix ---
  mix_kernel<<<128, 256, 0, stream>>>(eo, out_gates, out_mixed);
}